// Round 1
// baseline (827.898 us; speedup 1.0000x reference)
//
#include <hip/hip_runtime.h>
#include <cmath>

#define N_NODES 50000
#define N_EDGES 800000
#define F 128          // HEADS*HID
#define OUT_DIM 40
#define SLOPE 0.2f
#define EPS_DEN 1e-16f

// ---------------- GEMM: C[n,128] = A[n,128] @ W[128,128]^T + b ----------------
__global__ __launch_bounds__(256) void gemm_xw_bias(const float* __restrict__ A,
    const float* __restrict__ W, const float* __restrict__ b,
    float* __restrict__ C, int nrows) {
  const int K = 128;
  __shared__ float As[64][17];
  __shared__ float Bs[16][65];
  int tid = threadIdx.x;
  int tx = tid & 15, ty = tid >> 4;
  int row0 = blockIdx.x * 64;
  int col0 = blockIdx.y * 64;
  float acc[4][4] = {};
  for (int kc = 0; kc < K; kc += 16) {
#pragma unroll
    for (int i = 0; i < 4; ++i) {
      int idx = tid + 256 * i;
      int r = idx >> 4, kk = idx & 15;
      int gr = row0 + r;
      As[r][kk] = (gr < nrows) ? A[gr * K + kc + kk] : 0.f;
    }
#pragma unroll
    for (int i = 0; i < 4; ++i) {
      int idx = tid + 256 * i;
      int m = idx >> 4, kk = idx & 15;
      Bs[kk][m] = W[(col0 + m) * K + kc + kk];
    }
    __syncthreads();
#pragma unroll
    for (int kk = 0; kk < 16; ++kk) {
      float a[4], bb[4];
#pragma unroll
      for (int i = 0; i < 4; ++i) a[i] = As[ty * 4 + i][kk];
#pragma unroll
      for (int j = 0; j < 4; ++j) bb[j] = Bs[kk][tx * 4 + j];
#pragma unroll
      for (int i = 0; i < 4; ++i)
#pragma unroll
        for (int j = 0; j < 4; ++j) acc[i][j] += a[i] * bb[j];
    }
    __syncthreads();
  }
#pragma unroll
  for (int i = 0; i < 4; ++i) {
    int gr = row0 + ty * 4 + i;
    if (gr >= nrows) continue;
#pragma unroll
    for (int j = 0; j < 4; ++j) {
      int gc = col0 + tx * 4 + j;
      C[gr * F + gc] = acc[i][j] + b[gc];
    }
  }
}

// ---------------- per-node attention coefficients ----------------
__global__ __launch_bounds__(256) void alphas_kernel(const float* __restrict__ xt,
    const float* __restrict__ attl, const float* __restrict__ attr,
    float* __restrict__ al, float* __restrict__ ar, int n) {
  int node = (int)((blockIdx.x * blockDim.x + threadIdx.x) >> 6);
  int lane = threadIdx.x & 63;
  if (node >= n) return;
  float v0 = xt[node * F + lane];
  float v1 = xt[node * F + 64 + lane];
  float l0 = v0 * attl[lane * 2 + 0];
  float r0 = v0 * attr[lane * 2 + 0];
  float l1 = v1 * attl[lane * 2 + 1];
  float r1 = v1 * attr[lane * 2 + 1];
#pragma unroll
  for (int off = 32; off > 0; off >>= 1) {
    l0 += __shfl_down(l0, off, 64);
    r0 += __shfl_down(r0, off, 64);
    l1 += __shfl_down(l1, off, 64);
    r1 += __shfl_down(r1, off, 64);
  }
  if (lane == 0) {
    al[node * 2 + 0] = l0; al[node * 2 + 1] = l1;
    ar[node * 2 + 0] = r0; ar[node * 2 + 1] = r1;
  }
}

// ---------------- CSR build ----------------
__global__ void count_kernel(const int* __restrict__ ei, int* __restrict__ cnt) {
  int e = blockIdx.x * blockDim.x + threadIdx.x;
  if (e < N_EDGES) atomicAdd(&cnt[ei[N_EDGES + e]], 1);
}

__global__ __launch_bounds__(1024) void scan_kernel(const int* __restrict__ cnt,
    int* __restrict__ rowptr, int* __restrict__ cursor, int n) {
  __shared__ int wsum[16];
  __shared__ int s_carry;
  int tid = threadIdx.x;
  int lane = tid & 63, wid = tid >> 6;
  if (tid == 0) s_carry = 0;
  __syncthreads();
  for (int base = 0; base < n; base += 1024) {
    int i = base + tid;
    int v = (i < n) ? cnt[i] : 0;
    int x = v;
#pragma unroll
    for (int off = 1; off < 64; off <<= 1) {
      int t = __shfl_up(x, off, 64);
      if (lane >= off) x += t;
    }
    if (lane == 63) wsum[wid] = x;
    __syncthreads();
    int wpre = 0;
    for (int w = 0; w < wid; ++w) wpre += wsum[w];
    int carry = s_carry;
    int incl = carry + wpre + x;
    if (i < n) { rowptr[i + 1] = incl; cursor[i] = incl - v; }
    __syncthreads();
    if (tid == 1023) s_carry = incl;
    __syncthreads();
  }
  if (tid == 0) rowptr[0] = 0;
}

__global__ void fill_kernel(const int* __restrict__ ei, int* __restrict__ cursor,
                            int* __restrict__ srcs) {
  int e = blockIdx.x * blockDim.x + threadIdx.x;
  if (e < N_EDGES) {
    int dst = ei[N_EDGES + e];
    int pos = atomicAdd(&cursor[dst], 1);
    srcs[pos] = ei[e];
  }
}

// ---------------- fused GAT aggregation: one wave per destination node ----------------
__global__ __launch_bounds__(256) void aggregate_kernel(const int* __restrict__ rowptr,
    const int* __restrict__ srcs, const float* __restrict__ al, const float* __restrict__ ar,
    const float* __restrict__ xt, float* __restrict__ out, int n) {
  int node = (int)((blockIdx.x * blockDim.x + threadIdx.x) >> 6);
  int lane = threadIdx.x & 63;
  if (node >= n) return;
  int start = rowptr[node], end = rowptr[node + 1];
  float ar0 = ar[node * 2 + 0], ar1 = ar[node * 2 + 1];
  // pass 1: segment max (lane-parallel over edges)
  float m0 = -INFINITY, m1 = -INFINITY;
  for (int j = start + lane; j < end; j += 64) {
    int s = srcs[j];
    float s0 = al[s * 2 + 0] + ar0; s0 = (s0 > 0.f) ? s0 : SLOPE * s0;
    float s1 = al[s * 2 + 1] + ar1; s1 = (s1 > 0.f) ? s1 : SLOPE * s1;
    m0 = fmaxf(m0, s0); m1 = fmaxf(m1, s1);
  }
#pragma unroll
  for (int off = 32; off > 0; off >>= 1) {
    m0 = fmaxf(m0, __shfl_down(m0, off, 64));
    m1 = fmaxf(m1, __shfl_down(m1, off, 64));
  }
  m0 = __shfl(m0, 0, 64);
  m1 = __shfl(m1, 0, 64);
  // pass 2: serial over edges; wave-wide coalesced gather of xt[src]
  float acc0 = 0.f, acc1 = 0.f, d0 = 0.f, d1 = 0.f;
  for (int j = start; j < end; ++j) {
    int s = srcs[j];
    float s0 = al[s * 2 + 0] + ar0; s0 = (s0 > 0.f) ? s0 : SLOPE * s0;
    float s1 = al[s * 2 + 1] + ar1; s1 = (s1 > 0.f) ? s1 : SLOPE * s1;
    float e0 = __expf(s0 - m0);
    float e1 = __expf(s1 - m1);
    d0 += e0; d1 += e1;
    acc0 += e0 * xt[s * F + lane];
    acc1 += e1 * xt[s * F + 64 + lane];
  }
  float o0 = acc0 / (d0 + EPS_DEN);
  float o1 = acc1 / (d1 + EPS_DEN);
  out[node * F + lane]      = fmaxf(o0, 0.f);   // layer output relu
  out[node * F + 64 + lane] = fmaxf(o1, 0.f);
}

// ---------------- fused post_mp: Linear(128,64) -> Linear(64,40) -> log_softmax ----------------
__global__ __launch_bounds__(256) void post_kernel(const float* __restrict__ h,
    const float* __restrict__ Wp1, const float* __restrict__ bp1,
    const float* __restrict__ Wp2, const float* __restrict__ bp2,
    float* __restrict__ out, int n) {
  int node = (int)((blockIdx.x * blockDim.x + threadIdx.x) >> 6);
  int lane = threadIdx.x & 63;
  if (node >= n) return;
  // p1[lane] = bp1[lane] + h[node,:] . Wp1[lane,:]
  float p = bp1[lane];
  const float* hrow = h + (size_t)node * F;
  const float* w1row = Wp1 + lane * F;
  for (int k = 0; k < F; ++k) p += hrow[k] * w1row[k];
  // p2[o] = bp2[o] + sum_k p1[k] * Wp2[o,k]  (broadcast p1 via shuffles)
  int o = (lane < OUT_DIM) ? lane : 0;
  float z = 0.f;
  const float* w2row = Wp2 + o * 64;
  for (int k = 0; k < 64; ++k) z += __shfl(p, k, 64) * w2row[k];
  z += bp2[o];
  // log_softmax over 40 classes (lanes >= 40 neutral)
  float zm = (lane < OUT_DIM) ? z : -INFINITY;
#pragma unroll
  for (int off = 32; off > 0; off >>= 1) zm = fmaxf(zm, __shfl_xor(zm, off, 64));
  float ex = (lane < OUT_DIM) ? __expf(z - zm) : 0.f;
#pragma unroll
  for (int off = 32; off > 0; off >>= 1) ex += __shfl_xor(ex, off, 64);
  if (lane < OUT_DIM) out[(size_t)node * OUT_DIM + lane] = z - zm - logf(ex);
}

extern "C" void kernel_launch(void* const* d_in, const int* in_sizes, int n_in,
                              void* d_out, int out_size, void* d_ws, size_t ws_size,
                              hipStream_t stream) {
  const float* x   = (const float*)d_in[0];
  const int*   ei  = (const int*)d_in[1];
  const float* W1  = (const float*)d_in[2];
  const float* b1  = (const float*)d_in[3];
  const float* al1 = (const float*)d_in[4];
  const float* ar1 = (const float*)d_in[5];
  const float* W2  = (const float*)d_in[6];
  const float* b2  = (const float*)d_in[7];
  const float* al2 = (const float*)d_in[8];
  const float* ar2 = (const float*)d_in[9];
  const float* Wp1 = (const float*)d_in[10];
  const float* bp1 = (const float*)d_in[11];
  const float* Wp2 = (const float*)d_in[12];
  const float* bp2 = (const float*)d_in[13];
  float* out = (float*)d_out;

  float* bufA  = (float*)d_ws;                       // xt        [N,128]
  float* bufB  = bufA + (size_t)N_NODES * F;         // h         [N,128]
  float* al    = bufB + (size_t)N_NODES * F;         // [N,2]
  float* ar    = al + (size_t)N_NODES * 2;           // [N,2]
  int*   cnt   = (int*)(ar + (size_t)N_NODES * 2);   // [N]
  int*   rowptr= cnt + N_NODES;                      // [N+1]
  int*   cursor= rowptr + N_NODES + 1;               // [N]
  int*   srcs  = cursor + N_NODES;                   // [E]

  // ---- CSR by destination (edge_index shared by both layers) ----
  hipMemsetAsync(cnt, 0, N_NODES * sizeof(int), stream);
  count_kernel<<<(N_EDGES + 255) / 256, 256, 0, stream>>>(ei, cnt);
  scan_kernel<<<1, 1024, 0, stream>>>(cnt, rowptr, cursor, N_NODES);
  fill_kernel<<<(N_EDGES + 255) / 256, 256, 0, stream>>>(ei, cursor, srcs);

  dim3 ggrid((N_NODES + 63) / 64, 2);
  int nwgrid = (N_NODES + 3) / 4;  // 4 node-waves per 256-thread block

  // ---- layer 1 ----
  gemm_xw_bias<<<ggrid, 256, 0, stream>>>(x, W1, b1, bufA, N_NODES);
  alphas_kernel<<<nwgrid, 256, 0, stream>>>(bufA, al1, ar1, al, ar, N_NODES);
  aggregate_kernel<<<nwgrid, 256, 0, stream>>>(rowptr, srcs, al, ar, bufA, bufB, N_NODES);
  // ---- layer 2 ----
  gemm_xw_bias<<<ggrid, 256, 0, stream>>>(bufB, W2, b2, bufA, N_NODES);
  alphas_kernel<<<nwgrid, 256, 0, stream>>>(bufA, al2, ar2, al, ar, N_NODES);
  aggregate_kernel<<<nwgrid, 256, 0, stream>>>(rowptr, srcs, al, ar, bufA, bufB, N_NODES);
  // ---- post_mp + log_softmax ----
  post_kernel<<<nwgrid, 256, 0, stream>>>(bufB, Wp1, bp1, Wp2, bp2, out, N_NODES);
}

// Round 2
// 525.548 us; speedup vs baseline: 1.5753x; 1.5753x over previous
//
#include <hip/hip_runtime.h>
#include <cmath>

#define N_NODES 50000
#define N_EDGES 800000
#define F 128          // HEADS*HID
#define OUT_DIM 40
#define SLOPE 0.2f
#define EPS_DEN 1e-16f

// ---------------- GEMM: C[n,128] = A[n,128] @ W[128,128]^T + b ----------------
__global__ __launch_bounds__(256) void gemm_xw_bias(const float* __restrict__ A,
    const float* __restrict__ W, const float* __restrict__ b,
    float* __restrict__ C, int nrows) {
  const int K = 128;
  __shared__ float As[64][17];
  __shared__ float Bs[16][65];
  int tid = threadIdx.x;
  int tx = tid & 15, ty = tid >> 4;
  int row0 = blockIdx.x * 64;
  int col0 = blockIdx.y * 64;
  float acc[4][4] = {};
  for (int kc = 0; kc < K; kc += 16) {
#pragma unroll
    for (int i = 0; i < 4; ++i) {
      int idx = tid + 256 * i;
      int r = idx >> 4, kk = idx & 15;
      int gr = row0 + r;
      As[r][kk] = (gr < nrows) ? A[gr * K + kc + kk] : 0.f;
    }
#pragma unroll
    for (int i = 0; i < 4; ++i) {
      int idx = tid + 256 * i;
      int m = idx >> 4, kk = idx & 15;
      Bs[kk][m] = W[(col0 + m) * K + kc + kk];
    }
    __syncthreads();
#pragma unroll
    for (int kk = 0; kk < 16; ++kk) {
      float a[4], bb[4];
#pragma unroll
      for (int i = 0; i < 4; ++i) a[i] = As[ty * 4 + i][kk];
#pragma unroll
      for (int j = 0; j < 4; ++j) bb[j] = Bs[kk][tx * 4 + j];
#pragma unroll
      for (int i = 0; i < 4; ++i)
#pragma unroll
        for (int j = 0; j < 4; ++j) acc[i][j] += a[i] * bb[j];
    }
    __syncthreads();
  }
#pragma unroll
  for (int i = 0; i < 4; ++i) {
    int gr = row0 + ty * 4 + i;
    if (gr >= nrows) continue;
#pragma unroll
    for (int j = 0; j < 4; ++j) {
      int gc = col0 + tx * 4 + j;
      C[gr * F + gc] = acc[i][j] + b[gc];
    }
  }
}

// ---------------- per-node attention coefficients ----------------
__global__ __launch_bounds__(256) void alphas_kernel(const float* __restrict__ xt,
    const float* __restrict__ attl, const float* __restrict__ attr,
    float* __restrict__ al, float* __restrict__ ar, int n) {
  int node = (int)((blockIdx.x * blockDim.x + threadIdx.x) >> 6);
  int lane = threadIdx.x & 63;
  if (node >= n) return;
  float v0 = xt[(size_t)node * F + lane];
  float v1 = xt[(size_t)node * F + 64 + lane];
  float2 wl = *(const float2*)(attl + lane * 2);
  float2 wr = *(const float2*)(attr + lane * 2);
  float l0 = v0 * wl.x;
  float r0 = v0 * wr.x;
  float l1 = v1 * wl.y;
  float r1 = v1 * wr.y;
#pragma unroll
  for (int off = 32; off > 0; off >>= 1) {
    l0 += __shfl_down(l0, off, 64);
    r0 += __shfl_down(r0, off, 64);
    l1 += __shfl_down(l1, off, 64);
    r1 += __shfl_down(r1, off, 64);
  }
  if (lane == 0) {
    al[node * 2 + 0] = l0; al[node * 2 + 1] = l1;
    ar[node * 2 + 0] = r0; ar[node * 2 + 1] = r1;
  }
}

// ---------------- CSR build ----------------
__global__ void count_kernel(const int* __restrict__ ei, int* __restrict__ cnt) {
  int e = blockIdx.x * blockDim.x + threadIdx.x;
  if (e < N_EDGES) atomicAdd(&cnt[ei[N_EDGES + e]], 1);
}

// hierarchical scan: scan1 (block inclusive scans + block totals), scan2 (scan
// block totals, <=64 blocks), scan3 (add offsets, emit rowptr/cursor)
__global__ __launch_bounds__(1024) void scan1_kernel(const int* __restrict__ cnt,
    int* __restrict__ partial, int* __restrict__ bsum, int n) {
  __shared__ int wsum[16];
  int tid = threadIdx.x;
  int lane = tid & 63, wid = tid >> 6;
  int i = blockIdx.x * 1024 + tid;
  int v = (i < n) ? cnt[i] : 0;
  int x = v;
#pragma unroll
  for (int off = 1; off < 64; off <<= 1) {
    int t = __shfl_up(x, off, 64);
    if (lane >= off) x += t;
  }
  if (lane == 63) wsum[wid] = x;
  __syncthreads();
  if (wid == 0) {
    int w = (lane < 16) ? wsum[lane] : 0;
#pragma unroll
    for (int off = 1; off < 16; off <<= 1) {
      int t = __shfl_up(w, off, 64);
      if (lane >= off) w += t;
    }
    if (lane < 16) wsum[lane] = w;
  }
  __syncthreads();
  int pre = (wid > 0) ? wsum[wid - 1] : 0;
  x += pre;
  if (i < n) partial[i] = x;
  if (tid == 1023) bsum[blockIdx.x] = x;
}

__global__ void scan2_kernel(int* __restrict__ bsum, int nb) {
  int lane = threadIdx.x;
  int v = (lane < nb) ? bsum[lane] : 0;
  int x = v;
#pragma unroll
  for (int off = 1; off < 64; off <<= 1) {
    int t = __shfl_up(x, off, 64);
    if (lane >= off) x += t;
  }
  if (lane < nb) bsum[lane] = x - v;  // exclusive block offset
}

__global__ __launch_bounds__(1024) void scan3_kernel(const int* __restrict__ partial,
    const int* __restrict__ bsum, const int* __restrict__ cnt,
    int* __restrict__ rowptr, int* __restrict__ cursor, int n) {
  int i = blockIdx.x * 1024 + threadIdx.x;
  if (i < n) {
    int incl = partial[i] + bsum[blockIdx.x];
    rowptr[i + 1] = incl;
    cursor[i] = incl - cnt[i];
  }
  if (i == 0) rowptr[0] = 0;
}

__global__ void fill_kernel(const int* __restrict__ ei, int* __restrict__ cursor,
                            int* __restrict__ srcs) {
  int e = blockIdx.x * blockDim.x + threadIdx.x;
  if (e < N_EDGES) {
    int dst = ei[N_EDGES + e];
    int pos = atomicAdd(&cursor[dst], 1);
    srcs[pos] = ei[e];
  }
}

// ---------------- fused GAT aggregation: one wave per destination node ----------------
__global__ __launch_bounds__(256) void aggregate_kernel(const int* __restrict__ rowptr,
    const int* __restrict__ srcs, const float* __restrict__ al, const float* __restrict__ ar,
    const float* __restrict__ xt, float* __restrict__ out, int n) {
  __shared__ float ebuf0[4][64];
  __shared__ float ebuf1[4][64];
  __shared__ int   sbuf[4][64];
  int tid = threadIdx.x;
  int wid = tid >> 6, lane = tid & 63;
  int node = blockIdx.x * 4 + wid;
  if (node >= n) return;
  int start = rowptr[node], end = rowptr[node + 1];
  float2 arv = *(const float2*)(ar + (size_t)node * 2);
  float ar0 = arv.x, ar1 = arv.y;
  // pass 1: segment max (lane-parallel over edges)
  float m0 = -INFINITY, m1 = -INFINITY;
  for (int j = start + lane; j < end; j += 64) {
    int s = srcs[j];
    float2 a = *(const float2*)(al + (size_t)s * 2);
    float s0 = a.x + ar0; s0 = (s0 > 0.f) ? s0 : SLOPE * s0;
    float s1 = a.y + ar1; s1 = (s1 > 0.f) ? s1 : SLOPE * s1;
    m0 = fmaxf(m0, s0); m1 = fmaxf(m1, s1);
  }
#pragma unroll
  for (int off = 32; off > 0; off >>= 1) {
    m0 = fmaxf(m0, __shfl_xor(m0, off, 64));
    m1 = fmaxf(m1, __shfl_xor(m1, off, 64));
  }
  // pass 2: chunks of 64 edges — lane-parallel exp into LDS, then serial fma
  float acc0 = 0.f, acc1 = 0.f, d0 = 0.f, d1 = 0.f;
  for (int c = start; c < end; c += 64) {
    int j = c + lane;
    float e0 = 0.f, e1 = 0.f; int s = 0;
    if (j < end) {
      s = srcs[j];
      float2 a = *(const float2*)(al + (size_t)s * 2);
      float s0 = a.x + ar0; s0 = (s0 > 0.f) ? s0 : SLOPE * s0;
      float s1 = a.y + ar1; s1 = (s1 > 0.f) ? s1 : SLOPE * s1;
      e0 = __expf(s0 - m0); e1 = __expf(s1 - m1);
    }
    ebuf0[wid][lane] = e0; ebuf1[wid][lane] = e1; sbuf[wid][lane] = s;
    __builtin_amdgcn_wave_barrier();  // wave-internal LDS ordering (no block barrier)
    int cend = end - c; if (cend > 64) cend = 64;
    for (int t = 0; t < cend; ++t) {
      float e0t = ebuf0[wid][t];
      float e1t = ebuf1[wid][t];
      int st = sbuf[wid][t];
      d0 += e0t; d1 += e1t;
      const float* xr = xt + (size_t)st * F;
      acc0 += e0t * xr[lane];
      acc1 += e1t * xr[64 + lane];
    }
    __builtin_amdgcn_wave_barrier();
  }
  float o0 = acc0 / (d0 + EPS_DEN);
  float o1 = acc1 / (d1 + EPS_DEN);
  out[(size_t)node * F + lane]      = fmaxf(o0, 0.f);   // layer output relu
  out[(size_t)node * F + 64 + lane] = fmaxf(o1, 0.f);
}

// ---------------- fused post_mp: Linear(128,64) -> Linear(64,40) -> log_softmax ----
// Weights staged TRANSPOSED in LDS (Wt1[k][j]: lane j reads consecutive dwords,
// 2 lanes/bank = conflict-free on gfx950). 64 nodes/block amortize the staging.
__global__ __launch_bounds__(256) void post_kernel(const float* __restrict__ h,
    const float* __restrict__ Wp1, const float* __restrict__ bp1,
    const float* __restrict__ Wp2, const float* __restrict__ bp2,
    float* __restrict__ out, int n) {
  __shared__ float Wt1[128 * 64];      // 32 KB: Wt1[k*64 + j] = Wp1[j*128 + k]
  __shared__ float Wt2[64 * OUT_DIM];  // 10 KB: Wt2[k*40 + o] = Wp2[o*64 + k]
  __shared__ float hbuf[4][128];
  __shared__ float p1buf[4][64];
  int tid = threadIdx.x;
#pragma unroll
  for (int r = 0; r < 32; ++r) {
    int i = tid + 256 * r;             // 0..8191
    int j = i >> 7, k = i & 127;
    Wt1[k * 64 + j] = Wp1[i];
  }
#pragma unroll
  for (int r = 0; r < 10; ++r) {
    int i = tid + 256 * r;             // 0..2559
    int o = i >> 6, k = i & 63;
    Wt2[k * OUT_DIM + o] = Wp2[i];
  }
  __syncthreads();
  int wid = tid >> 6, lane = tid & 63;
  int o = (lane < OUT_DIM) ? lane : 0;
  float b1v = bp1[lane];
  float b2v = bp2[o];
  int base = blockIdx.x * 64 + wid * 16;
  for (int r = 0; r < 16; ++r) {
    int node = base + r;
    if (node >= n) break;              // no block barriers below — safe divergence
    const float* hrow = h + (size_t)node * F;
    hbuf[wid][lane]      = hrow[lane];
    hbuf[wid][lane + 64] = hrow[lane + 64];
    __builtin_amdgcn_wave_barrier();
    float p = b1v;
#pragma unroll 16
    for (int k = 0; k < 128; ++k) p += hbuf[wid][k] * Wt1[k * 64 + lane];
    p1buf[wid][lane] = p;
    __builtin_amdgcn_wave_barrier();
    float z = b2v;
#pragma unroll 16
    for (int k = 0; k < 64; ++k) z += p1buf[wid][k] * Wt2[k * OUT_DIM + o];
    float zm = (lane < OUT_DIM) ? z : -INFINITY;
#pragma unroll
    for (int off = 32; off > 0; off >>= 1) zm = fmaxf(zm, __shfl_xor(zm, off, 64));
    float ex = (lane < OUT_DIM) ? __expf(z - zm) : 0.f;
#pragma unroll
    for (int off = 32; off > 0; off >>= 1) ex += __shfl_xor(ex, off, 64);
    if (lane < OUT_DIM) out[(size_t)node * OUT_DIM + lane] = z - zm - logf(ex);
    __builtin_amdgcn_wave_barrier();
  }
}

extern "C" void kernel_launch(void* const* d_in, const int* in_sizes, int n_in,
                              void* d_out, int out_size, void* d_ws, size_t ws_size,
                              hipStream_t stream) {
  const float* x   = (const float*)d_in[0];
  const int*   ei  = (const int*)d_in[1];
  const float* W1  = (const float*)d_in[2];
  const float* b1  = (const float*)d_in[3];
  const float* al1 = (const float*)d_in[4];
  const float* ar1 = (const float*)d_in[5];
  const float* W2  = (const float*)d_in[6];
  const float* b2  = (const float*)d_in[7];
  const float* al2 = (const float*)d_in[8];
  const float* ar2 = (const float*)d_in[9];
  const float* Wp1 = (const float*)d_in[10];
  const float* bp1 = (const float*)d_in[11];
  const float* Wp2 = (const float*)d_in[12];
  const float* bp2 = (const float*)d_in[13];
  float* out = (float*)d_out;

  float* bufA  = (float*)d_ws;                       // xt        [N,128]
  float* bufB  = bufA + (size_t)N_NODES * F;         // h         [N,128]
  float* al    = bufB + (size_t)N_NODES * F;         // [N,2]
  float* ar    = al + (size_t)N_NODES * 2;           // [N,2]
  int*   cnt   = (int*)(ar + (size_t)N_NODES * 2);   // [N]
  int*   rowptr= cnt + N_NODES;                      // [N+1]
  int*   cursor= rowptr + N_NODES + 1;               // [N]
  int*   srcs  = cursor + N_NODES;                   // [E]
  // scan scratch aliases (used only during CSR build, before al/srcs are live):
  int*   partial = srcs;                             // [N] into srcs
  int*   bsum    = (int*)al;                         // [64] into al

  const int SCAN_BLOCKS = (N_NODES + 1023) / 1024;   // 49

  // ---- CSR by destination (edge_index shared by both layers) ----
  hipMemsetAsync(cnt, 0, N_NODES * sizeof(int), stream);
  count_kernel<<<(N_EDGES + 255) / 256, 256, 0, stream>>>(ei, cnt);
  scan1_kernel<<<SCAN_BLOCKS, 1024, 0, stream>>>(cnt, partial, bsum, N_NODES);
  scan2_kernel<<<1, 64, 0, stream>>>(bsum, SCAN_BLOCKS);
  scan3_kernel<<<SCAN_BLOCKS, 1024, 0, stream>>>(partial, bsum, cnt, rowptr, cursor, N_NODES);
  fill_kernel<<<(N_EDGES + 255) / 256, 256, 0, stream>>>(ei, cursor, srcs);

  dim3 ggrid((N_NODES + 63) / 64, 2);
  int nwgrid = (N_NODES + 3) / 4;  // 4 node-waves per 256-thread block

  // ---- layer 1 ----
  gemm_xw_bias<<<ggrid, 256, 0, stream>>>(x, W1, b1, bufA, N_NODES);
  alphas_kernel<<<nwgrid, 256, 0, stream>>>(bufA, al1, ar1, al, ar, N_NODES);
  aggregate_kernel<<<nwgrid, 256, 0, stream>>>(rowptr, srcs, al, ar, bufA, bufB, N_NODES);
  // ---- layer 2 ----
  gemm_xw_bias<<<ggrid, 256, 0, stream>>>(bufB, W2, b2, bufA, N_NODES);
  alphas_kernel<<<nwgrid, 256, 0, stream>>>(bufA, al2, ar2, al, ar, N_NODES);
  aggregate_kernel<<<nwgrid, 256, 0, stream>>>(rowptr, srcs, al, ar, bufA, bufB, N_NODES);
  // ---- post_mp + log_softmax ----
  post_kernel<<<(N_NODES + 63) / 64, 256, 0, stream>>>(bufB, Wp1, bp1, Wp2, bp2, out, N_NODES);
}

// Round 3
// 466.239 us; speedup vs baseline: 1.7757x; 1.1272x over previous
//
#include <hip/hip_runtime.h>
#include <cmath>

#define N_NODES 50000
#define N_EDGES 800000
#define F 128          // HEADS*HID
#define OUT_DIM 40
#define SLOPE 0.2f
#define EPS_DEN 1e-16f

// ---------------- GEMM: C[n,128] = A[n,128] @ W[128,128]^T + b ----------------
__global__ __launch_bounds__(256) void gemm_xw_bias(const float* __restrict__ A,
    const float* __restrict__ W, const float* __restrict__ b,
    float* __restrict__ C, int nrows) {
  const int K = 128;
  __shared__ float As[64][17];
  __shared__ float Bs[16][65];
  int tid = threadIdx.x;
  int tx = tid & 15, ty = tid >> 4;
  int row0 = blockIdx.x * 64;
  int col0 = blockIdx.y * 64;
  float acc[4][4] = {};
  for (int kc = 0; kc < K; kc += 16) {
#pragma unroll
    for (int i = 0; i < 4; ++i) {
      int idx = tid + 256 * i;
      int r = idx >> 4, kk = idx & 15;
      int gr = row0 + r;
      As[r][kk] = (gr < nrows) ? A[gr * K + kc + kk] : 0.f;
    }
#pragma unroll
    for (int i = 0; i < 4; ++i) {
      int idx = tid + 256 * i;
      int m = idx >> 4, kk = idx & 15;
      Bs[kk][m] = W[(col0 + m) * K + kc + kk];
    }
    __syncthreads();
#pragma unroll
    for (int kk = 0; kk < 16; ++kk) {
      float a[4], bb[4];
#pragma unroll
      for (int i = 0; i < 4; ++i) a[i] = As[ty * 4 + i][kk];
#pragma unroll
      for (int j = 0; j < 4; ++j) bb[j] = Bs[kk][tx * 4 + j];
#pragma unroll
      for (int i = 0; i < 4; ++i)
#pragma unroll
        for (int j = 0; j < 4; ++j) acc[i][j] += a[i] * bb[j];
    }
    __syncthreads();
  }
#pragma unroll
  for (int i = 0; i < 4; ++i) {
    int gr = row0 + ty * 4 + i;
    if (gr >= nrows) continue;
#pragma unroll
    for (int j = 0; j < 4; ++j) {
      int gc = col0 + tx * 4 + j;
      C[gr * F + gc] = acc[i][j] + b[gc];
    }
  }
}

// ---------------- per-node attention coefficients ----------------
__global__ __launch_bounds__(256) void alphas_kernel(const float* __restrict__ xt,
    const float* __restrict__ attl, const float* __restrict__ attr,
    float* __restrict__ al, float* __restrict__ ar, int n) {
  int node = (int)((blockIdx.x * blockDim.x + threadIdx.x) >> 6);
  int lane = threadIdx.x & 63;
  if (node >= n) return;
  float v0 = xt[(size_t)node * F + lane];
  float v1 = xt[(size_t)node * F + 64 + lane];
  float2 wl = *(const float2*)(attl + lane * 2);
  float2 wr = *(const float2*)(attr + lane * 2);
  float l0 = v0 * wl.x;
  float r0 = v0 * wr.x;
  float l1 = v1 * wl.y;
  float r1 = v1 * wr.y;
#pragma unroll
  for (int off = 32; off > 0; off >>= 1) {
    l0 += __shfl_down(l0, off, 64);
    r0 += __shfl_down(r0, off, 64);
    l1 += __shfl_down(l1, off, 64);
    r1 += __shfl_down(r1, off, 64);
  }
  if (lane == 0) {
    al[node * 2 + 0] = l0; al[node * 2 + 1] = l1;
    ar[node * 2 + 0] = r0; ar[node * 2 + 1] = r1;
  }
}

// ---------------- CSR build ----------------
__global__ void count_kernel(const int* __restrict__ ei, int* __restrict__ cnt) {
  int e = blockIdx.x * blockDim.x + threadIdx.x;
  if (e < N_EDGES) atomicAdd(&cnt[ei[N_EDGES + e]], 1);
}

__global__ __launch_bounds__(1024) void scan1_kernel(const int* __restrict__ cnt,
    int* __restrict__ partial, int* __restrict__ bsum, int n) {
  __shared__ int wsum[16];
  int tid = threadIdx.x;
  int lane = tid & 63, wid = tid >> 6;
  int i = blockIdx.x * 1024 + tid;
  int v = (i < n) ? cnt[i] : 0;
  int x = v;
#pragma unroll
  for (int off = 1; off < 64; off <<= 1) {
    int t = __shfl_up(x, off, 64);
    if (lane >= off) x += t;
  }
  if (lane == 63) wsum[wid] = x;
  __syncthreads();
  if (wid == 0) {
    int w = (lane < 16) ? wsum[lane] : 0;
#pragma unroll
    for (int off = 1; off < 16; off <<= 1) {
      int t = __shfl_up(w, off, 64);
      if (lane >= off) w += t;
    }
    if (lane < 16) wsum[lane] = w;
  }
  __syncthreads();
  int pre = (wid > 0) ? wsum[wid - 1] : 0;
  x += pre;
  if (i < n) partial[i] = x;
  if (tid == 1023) bsum[blockIdx.x] = x;
}

__global__ void scan2_kernel(int* __restrict__ bsum, int nb) {
  int lane = threadIdx.x;
  int v = (lane < nb) ? bsum[lane] : 0;
  int x = v;
#pragma unroll
  for (int off = 1; off < 64; off <<= 1) {
    int t = __shfl_up(x, off, 64);
    if (lane >= off) x += t;
  }
  if (lane < nb) bsum[lane] = x - v;  // exclusive block offset
}

__global__ __launch_bounds__(1024) void scan3_kernel(const int* __restrict__ partial,
    const int* __restrict__ bsum, const int* __restrict__ cnt,
    int* __restrict__ rowptr, int* __restrict__ cursor, int n) {
  int i = blockIdx.x * 1024 + threadIdx.x;
  if (i < n) {
    int incl = partial[i] + bsum[blockIdx.x];
    rowptr[i + 1] = incl;
    cursor[i] = incl - cnt[i];
  }
  if (i == 0) rowptr[0] = 0;
}

__global__ void fill_kernel(const int* __restrict__ ei, int* __restrict__ cursor,
                            int* __restrict__ srcs) {
  int e = blockIdx.x * blockDim.x + threadIdx.x;
  if (e < N_EDGES) {
    int dst = ei[N_EDGES + e];
    int pos = atomicAdd(&cursor[dst], 1);
    srcs[pos] = ei[e];
  }
}

// ---------------- fused GAT aggregation: one wave per destination node ----------
// pass 2 processes edge PAIRS: lanes 0-31 gather edge t's 512B row as float4,
// lanes 32-63 edge t+1. Denominators accumulated lane-parallel in score phase.
__global__ __launch_bounds__(256) void aggregate_kernel(const int* __restrict__ rowptr,
    const int* __restrict__ srcs, const float* __restrict__ al, const float* __restrict__ ar,
    const float* __restrict__ xt, float* __restrict__ out, int n) {
  __shared__ float ebuf0[4][64];
  __shared__ float ebuf1[4][64];
  __shared__ int   sbuf[4][64];
  int tid = threadIdx.x;
  int wid = tid >> 6, lane = tid & 63;
  int half = lane >> 5, hl = lane & 31;
  int node = blockIdx.x * 4 + wid;
  if (node >= n) return;
  int start = rowptr[node], end = rowptr[node + 1];
  float2 arv = *(const float2*)(ar + (size_t)node * 2);
  float ar0 = arv.x, ar1 = arv.y;
  // pass 1: segment max (lane-parallel over edges)
  float m0 = -INFINITY, m1 = -INFINITY;
  for (int j = start + lane; j < end; j += 64) {
    int s = srcs[j];
    float2 a = *(const float2*)(al + (size_t)s * 2);
    float s0 = a.x + ar0; s0 = (s0 > 0.f) ? s0 : SLOPE * s0;
    float s1 = a.y + ar1; s1 = (s1 > 0.f) ? s1 : SLOPE * s1;
    m0 = fmaxf(m0, s0); m1 = fmaxf(m1, s1);
  }
#pragma unroll
  for (int off = 32; off > 0; off >>= 1) {
    m0 = fmaxf(m0, __shfl_xor(m0, off, 64));
    m1 = fmaxf(m1, __shfl_xor(m1, off, 64));
  }
  // pass 2
  float acc[4] = {0.f, 0.f, 0.f, 0.f};
  float dl0 = 0.f, dl1 = 0.f;
  for (int c = start; c < end; c += 64) {
    int j = c + lane;
    float e0 = 0.f, e1 = 0.f; int s = 0;
    if (j < end) {
      s = srcs[j];
      float2 a = *(const float2*)(al + (size_t)s * 2);
      float s0 = a.x + ar0; s0 = (s0 > 0.f) ? s0 : SLOPE * s0;
      float s1 = a.y + ar1; s1 = (s1 > 0.f) ? s1 : SLOPE * s1;
      e0 = __expf(s0 - m0); e1 = __expf(s1 - m1);
    }
    dl0 += e0; dl1 += e1;
    ebuf0[wid][lane] = e0; ebuf1[wid][lane] = e1; sbuf[wid][lane] = s;
    __builtin_amdgcn_wave_barrier();
    int cend = end - c; if (cend > 64) cend = 64;
#pragma unroll 2
    for (int t = 0; t < cend; t += 2) {
      int th = t + half;
      if (th < cend) {
        int st = sbuf[wid][th];
        float w = (hl < 16) ? ebuf0[wid][th] : ebuf1[wid][th];
        float4 v = *(const float4*)(xt + (size_t)st * F + hl * 4);
        acc[0] += w * v.x; acc[1] += w * v.y;
        acc[2] += w * v.z; acc[3] += w * v.w;
      }
    }
    __builtin_amdgcn_wave_barrier();
  }
  // denominators: reduce across all 64 lanes
#pragma unroll
  for (int off = 32; off > 0; off >>= 1) {
    dl0 += __shfl_xor(dl0, off, 64);
    dl1 += __shfl_xor(dl1, off, 64);
  }
  // combine parity halves: lane l and l^32 hold same features
#pragma unroll
  for (int q = 0; q < 4; ++q) acc[q] += __shfl_xor(acc[q], 32, 64);
  if (half == 0) {
    float d = (hl < 16) ? dl0 : dl1;
    float inv = 1.f / (d + EPS_DEN);
    float4 o;
    o.x = fmaxf(acc[0] * inv, 0.f);
    o.y = fmaxf(acc[1] * inv, 0.f);
    o.z = fmaxf(acc[2] * inv, 0.f);
    o.w = fmaxf(acc[3] * inv, 0.f);
    *(float4*)(out + (size_t)node * F + hl * 4) = o;
  }
}

// ---------------- combine post_mp weights: Wc = Wp2@Wp1 (no activation between!)
// Wc stored TRANSPOSED+padded in global: Wct[k*48 + o], o<40, k<128. bc[o].
__global__ void combine_kernel(const float* __restrict__ Wp1, const float* __restrict__ bp1,
    const float* __restrict__ Wp2, const float* __restrict__ bp2,
    float* __restrict__ Wct, float* __restrict__ bc) {
  int idx = blockIdx.x * 256 + threadIdx.x;
  if (blockIdx.x < 20) {                 // 5120 Wc entries
    int o = idx >> 7, k = idx & 127;
    float s = 0.f;
#pragma unroll 8
    for (int j = 0; j < 64; ++j) s += Wp2[o * 64 + j] * Wp1[j * 128 + k];
    Wct[k * 48 + o] = s;
  } else if (threadIdx.x < OUT_DIM) {    // bc
    int o = threadIdx.x;
    float s = bp2[o];
    for (int j = 0; j < 64; ++j) s += Wp2[o * 64 + j] * bp1[j];
    bc[o] = s;
  }
}

// ---------------- post GEMM + log_softmax: out[n,40] = h[n,128]@Wc^T + bc ------
// 128-node tile / block; 256 threads as (ty=tid>>3: 4 rows each, tx=tid&7: 5 cols
// each). 20 FMA per 9 LDS reads. Softmax reduced across the 8 tx lanes via shfl.
__global__ __launch_bounds__(256) void post_kernel(const float* __restrict__ h,
    const float* __restrict__ Wct_g, const float* __restrict__ bc,
    float* __restrict__ out, int n) {
  __shared__ float Wct[128 * 48];        // [k][o] padded to 48 → 24 KB
  __shared__ float hs[128 * 33];         // [node][kk] kk-chunk of 32, pad 33 → 16.9 KB
  int tid = threadIdx.x;
#pragma unroll
  for (int r = 0; r < 24; ++r) {         // linear copy: coalesced + conflict-free
    int i = tid + 256 * r;               // 0..6143
    Wct[i] = Wct_g[i];
  }
  int tx = tid & 7, ty = tid >> 3;
  int base = blockIdx.x * 128;
  float z[4][5] = {};
  for (int kc = 0; kc < 128; kc += 32) {
    __syncthreads();
#pragma unroll
    for (int r = 0; r < 16; ++r) {
      int i = tid + 256 * r;             // 0..4095
      int nd = i >> 5, kk = i & 31;
      int gn = base + nd;
      hs[nd * 33 + kk] = (gn < n) ? h[(size_t)gn * F + kc + kk] : 0.f;
    }
    __syncthreads();
#pragma unroll 8
    for (int kk = 0; kk < 32; ++kk) {
      float a[4], b[5];
#pragma unroll
      for (int i = 0; i < 4; ++i) a[i] = hs[(ty * 4 + i) * 33 + kk];
#pragma unroll
      for (int c = 0; c < 5; ++c) b[c] = Wct[(kc + kk) * 48 + tx * 5 + c];
#pragma unroll
      for (int i = 0; i < 4; ++i)
#pragma unroll
        for (int c = 0; c < 5; ++c) z[i][c] += a[i] * b[c];
    }
  }
  float bcv[5];
#pragma unroll
  for (int c = 0; c < 5; ++c) bcv[c] = bc[tx * 5 + c];
#pragma unroll
  for (int i = 0; i < 4; ++i) {
    int node = base + ty * 4 + i;
    if (node >= n) continue;             // whole 8-lane tx-group shares `node`
    float zc[5], m = -INFINITY;
#pragma unroll
    for (int c = 0; c < 5; ++c) { zc[c] = z[i][c] + bcv[c]; m = fmaxf(m, zc[c]); }
    m = fmaxf(m, __shfl_xor(m, 1, 64));
    m = fmaxf(m, __shfl_xor(m, 2, 64));
    m = fmaxf(m, __shfl_xor(m, 4, 64));
    float s = 0.f;
#pragma unroll
    for (int c = 0; c < 5; ++c) s += __expf(zc[c] - m);
    s += __shfl_xor(s, 1, 64);
    s += __shfl_xor(s, 2, 64);
    s += __shfl_xor(s, 4, 64);
    float ls = logf(s);
#pragma unroll
    for (int c = 0; c < 5; ++c)
      out[(size_t)node * OUT_DIM + tx * 5 + c] = zc[c] - m - ls;
  }
}

extern "C" void kernel_launch(void* const* d_in, const int* in_sizes, int n_in,
                              void* d_out, int out_size, void* d_ws, size_t ws_size,
                              hipStream_t stream) {
  const float* x   = (const float*)d_in[0];
  const int*   ei  = (const int*)d_in[1];
  const float* W1  = (const float*)d_in[2];
  const float* b1  = (const float*)d_in[3];
  const float* al1 = (const float*)d_in[4];
  const float* ar1 = (const float*)d_in[5];
  const float* W2  = (const float*)d_in[6];
  const float* b2  = (const float*)d_in[7];
  const float* al2 = (const float*)d_in[8];
  const float* ar2 = (const float*)d_in[9];
  const float* Wp1 = (const float*)d_in[10];
  const float* bp1 = (const float*)d_in[11];
  const float* Wp2 = (const float*)d_in[12];
  const float* bp2 = (const float*)d_in[13];
  float* out = (float*)d_out;

  float* bufA  = (float*)d_ws;                       // xt        [N,128]
  float* bufB  = bufA + (size_t)N_NODES * F;         // h         [N,128]
  float* al    = bufB + (size_t)N_NODES * F;         // [N,2]
  float* ar    = al + (size_t)N_NODES * 2;           // [N,2]
  int*   cnt   = (int*)(ar + (size_t)N_NODES * 2);   // [N]
  int*   rowptr= cnt + N_NODES;                      // [N+1]
  int*   cursor= rowptr + N_NODES + 1;               // [N]
  int*   srcs  = cursor + N_NODES;                   // [E]
  float* Wct   = (float*)(srcs + N_EDGES);           // [128*48]
  float* bc    = Wct + 128 * 48;                     // [40]
  // scan scratch aliases (used only during CSR build, before al/srcs are live):
  int*   partial = srcs;                             // [N] into srcs
  int*   bsum    = (int*)al;                         // [64] into al

  const int SCAN_BLOCKS = (N_NODES + 1023) / 1024;   // 49

  // ---- CSR by destination (edge_index shared by both layers) ----
  hipMemsetAsync(cnt, 0, N_NODES * sizeof(int), stream);
  count_kernel<<<(N_EDGES + 255) / 256, 256, 0, stream>>>(ei, cnt);
  scan1_kernel<<<SCAN_BLOCKS, 1024, 0, stream>>>(cnt, partial, bsum, N_NODES);
  scan2_kernel<<<1, 64, 0, stream>>>(bsum, SCAN_BLOCKS);
  scan3_kernel<<<SCAN_BLOCKS, 1024, 0, stream>>>(partial, bsum, cnt, rowptr, cursor, N_NODES);
  fill_kernel<<<(N_EDGES + 255) / 256, 256, 0, stream>>>(ei, cursor, srcs);
  combine_kernel<<<21, 256, 0, stream>>>(Wp1, bp1, Wp2, bp2, Wct, bc);

  dim3 ggrid((N_NODES + 63) / 64, 2);
  int nwgrid = (N_NODES + 3) / 4;  // 4 node-waves per 256-thread block

  // ---- layer 1 ----
  gemm_xw_bias<<<ggrid, 256, 0, stream>>>(x, W1, b1, bufA, N_NODES);
  alphas_kernel<<<nwgrid, 256, 0, stream>>>(bufA, al1, ar1, al, ar, N_NODES);
  aggregate_kernel<<<nwgrid, 256, 0, stream>>>(rowptr, srcs, al, ar, bufA, bufB, N_NODES);
  // ---- layer 2 ----
  gemm_xw_bias<<<ggrid, 256, 0, stream>>>(bufB, W2, b2, bufA, N_NODES);
  alphas_kernel<<<nwgrid, 256, 0, stream>>>(bufA, al2, ar2, al, ar, N_NODES);
  aggregate_kernel<<<nwgrid, 256, 0, stream>>>(rowptr, srcs, al, ar, bufA, bufB, N_NODES);
  // ---- post_mp + log_softmax ----
  post_kernel<<<(N_NODES + 127) / 128, 256, 0, stream>>>(bufB, Wct, bc, out, N_NODES);
}

// Round 4
// 399.324 us; speedup vs baseline: 2.0732x; 1.1676x over previous
//
#include <hip/hip_runtime.h>
#include <hip/hip_fp16.h>
#include <cmath>

#define N_NODES 50000
#define N_EDGES 800000
#define F 128          // HEADS*HID
#define OUT_DIM 40
#define SLOPE 0.2f
#define EPS_DEN 1e-16f

// ------- GEMM: Ch[n,128] = fp16( A[n,128] @ W[128,128]^T + b ), fp32 accumulate
// LDS operands stored [k][m]: fragment loads are ds_read_b128 (broadcast / 2-way).
__global__ __launch_bounds__(256) void gemm_xw_fp16(const float* __restrict__ A,
    const float* __restrict__ W, const float* __restrict__ b,
    __half* __restrict__ Ch, int nrows) {
  const int K = 128;
  __shared__ float Ast[32][68];   // [kk][row]
  __shared__ float Bst[32][68];   // [kk][col]
  int tid = threadIdx.x;
  int tx = tid & 15, ty = tid >> 4;
  int row0 = blockIdx.x * 64;
  int col0 = blockIdx.y * 64;
  float acc[4][4] = {};
  for (int kc = 0; kc < K; kc += 32) {
#pragma unroll
    for (int l = 0; l < 2; ++l) {
      int i = tid + 256 * l;        // 0..511
      int r = i >> 3, k4 = i & 7;   // r: 0..63, k4: 0..7
      int gr = row0 + r;
      float4 v = (gr < nrows) ? *(const float4*)(A + (size_t)gr * K + kc + k4 * 4)
                              : make_float4(0.f, 0.f, 0.f, 0.f);
      Ast[k4 * 4 + 0][r] = v.x; Ast[k4 * 4 + 1][r] = v.y;
      Ast[k4 * 4 + 2][r] = v.z; Ast[k4 * 4 + 3][r] = v.w;
      float4 w4 = *(const float4*)(W + (size_t)(col0 + r) * K + kc + k4 * 4);
      Bst[k4 * 4 + 0][r] = w4.x; Bst[k4 * 4 + 1][r] = w4.y;
      Bst[k4 * 4 + 2][r] = w4.z; Bst[k4 * 4 + 3][r] = w4.w;
    }
    __syncthreads();
#pragma unroll
    for (int kk = 0; kk < 32; ++kk) {
      float4 a4 = *(const float4*)&Ast[kk][ty * 4];
      float4 b4 = *(const float4*)&Bst[kk][tx * 4];
      float a[4] = {a4.x, a4.y, a4.z, a4.w};
      float bb[4] = {b4.x, b4.y, b4.z, b4.w};
#pragma unroll
      for (int i = 0; i < 4; ++i)
#pragma unroll
        for (int j = 0; j < 4; ++j) acc[i][j] += a[i] * bb[j];
    }
    __syncthreads();
  }
  int gc = col0 + tx * 4;
  float b0 = b[gc], b1v = b[gc + 1], b2v = b[gc + 2], b3 = b[gc + 3];
#pragma unroll
  for (int i = 0; i < 4; ++i) {
    int gr = row0 + ty * 4 + i;
    if (gr >= nrows) continue;
    __half2 h0 = __floats2half2_rn(acc[i][0] + b0, acc[i][1] + b1v);
    __half2 h1 = __floats2half2_rn(acc[i][2] + b2v, acc[i][3] + b3);
    __half2* dst = (__half2*)(Ch + (size_t)gr * K + gc);
    dst[0] = h0; dst[1] = h1;
  }
}

// ---------------- per-node attention coefficients (reads fp16 xt) --------------
__global__ __launch_bounds__(256) void alphas_kernel(const __half* __restrict__ xh,
    const float* __restrict__ attl, const float* __restrict__ attr,
    float* __restrict__ al, float* __restrict__ ar, int n) {
  int node = (int)((blockIdx.x * blockDim.x + threadIdx.x) >> 6);
  int lane = threadIdx.x & 63;
  if (node >= n) return;
  float v0 = __half2float(xh[(size_t)node * F + lane]);
  float v1 = __half2float(xh[(size_t)node * F + 64 + lane]);
  float2 wl = *(const float2*)(attl + lane * 2);
  float2 wr = *(const float2*)(attr + lane * 2);
  float l0 = v0 * wl.x;
  float r0 = v0 * wr.x;
  float l1 = v1 * wl.y;
  float r1 = v1 * wr.y;
#pragma unroll
  for (int off = 32; off > 0; off >>= 1) {
    l0 += __shfl_down(l0, off, 64);
    r0 += __shfl_down(r0, off, 64);
    l1 += __shfl_down(l1, off, 64);
    r1 += __shfl_down(r1, off, 64);
  }
  if (lane == 0) {
    al[node * 2 + 0] = l0; al[node * 2 + 1] = l1;
    ar[node * 2 + 0] = r0; ar[node * 2 + 1] = r1;
  }
}

// ---------------- CSR build ----------------
__global__ void count_kernel(const int* __restrict__ ei, int* __restrict__ cnt) {
  int e = blockIdx.x * blockDim.x + threadIdx.x;
  if (e < N_EDGES) atomicAdd(&cnt[ei[N_EDGES + e]], 1);
}

__global__ __launch_bounds__(1024) void scan1_kernel(const int* __restrict__ cnt,
    int* __restrict__ partial, int* __restrict__ bsum, int n) {
  __shared__ int wsum[16];
  int tid = threadIdx.x;
  int lane = tid & 63, wid = tid >> 6;
  int i = blockIdx.x * 1024 + tid;
  int v = (i < n) ? cnt[i] : 0;
  int x = v;
#pragma unroll
  for (int off = 1; off < 64; off <<= 1) {
    int t = __shfl_up(x, off, 64);
    if (lane >= off) x += t;
  }
  if (lane == 63) wsum[wid] = x;
  __syncthreads();
  if (wid == 0) {
    int w = (lane < 16) ? wsum[lane] : 0;
#pragma unroll
    for (int off = 1; off < 16; off <<= 1) {
      int t = __shfl_up(w, off, 64);
      if (lane >= off) w += t;
    }
    if (lane < 16) wsum[lane] = w;
  }
  __syncthreads();
  int pre = (wid > 0) ? wsum[wid - 1] : 0;
  x += pre;
  if (i < n) partial[i] = x;
  if (tid == 1023) bsum[blockIdx.x] = x;
}

__global__ void scan2_kernel(int* __restrict__ bsum, int nb) {
  int lane = threadIdx.x;
  int v = (lane < nb) ? bsum[lane] : 0;
  int x = v;
#pragma unroll
  for (int off = 1; off < 64; off <<= 1) {
    int t = __shfl_up(x, off, 64);
    if (lane >= off) x += t;
  }
  if (lane < nb) bsum[lane] = x - v;  // exclusive block offset
}

__global__ __launch_bounds__(1024) void scan3_kernel(const int* __restrict__ partial,
    const int* __restrict__ bsum, const int* __restrict__ cnt,
    int* __restrict__ rowptr, int* __restrict__ cursor, int n) {
  int i = blockIdx.x * 1024 + threadIdx.x;
  if (i < n) {
    int incl = partial[i] + bsum[blockIdx.x];
    rowptr[i + 1] = incl;
    cursor[i] = incl - cnt[i];
  }
  if (i == 0) rowptr[0] = 0;
}

__global__ void fill_kernel(const int* __restrict__ ei, int* __restrict__ cursor,
                            int* __restrict__ srcs) {
  int e = blockIdx.x * blockDim.x + threadIdx.x;
  if (e < N_EDGES) {
    int dst = ei[N_EDGES + e];
    int pos = atomicAdd(&cursor[dst], 1);
    srcs[pos] = ei[e];
  }
}

// ---------------- fused GAT aggregation: one wave per destination node ----------
// Single pass (softmax shift-invariance: scores O(1), exp can't overflow fp32).
// Edge pairs: lanes 0-31 gather edge t's 256B fp16 row, lanes 32-63 edge t+1.
__global__ __launch_bounds__(256) void aggregate_kernel(const int* __restrict__ rowptr,
    const int* __restrict__ srcs, const float* __restrict__ al, const float* __restrict__ ar,
    const __half* __restrict__ xh, float* __restrict__ out, int n) {
  __shared__ float ebuf0[4][64];
  __shared__ float ebuf1[4][64];
  __shared__ int   sbuf[4][64];
  int tid = threadIdx.x;
  int wid = tid >> 6, lane = tid & 63;
  int half_ = lane >> 5, hl = lane & 31;
  int node = blockIdx.x * 4 + wid;
  if (node >= n) return;
  int start = rowptr[node], end = rowptr[node + 1];
  float2 arv = *(const float2*)(ar + (size_t)node * 2);
  float ar0 = arv.x, ar1 = arv.y;
  float acc[4] = {0.f, 0.f, 0.f, 0.f};
  float dl0 = 0.f, dl1 = 0.f;
  for (int c = start; c < end; c += 64) {
    int j = c + lane;
    float e0 = 0.f, e1 = 0.f; int s = 0;
    if (j < end) {
      s = srcs[j];
      float2 a = *(const float2*)(al + (size_t)s * 2);
      float s0 = a.x + ar0; s0 = (s0 > 0.f) ? s0 : SLOPE * s0;
      float s1 = a.y + ar1; s1 = (s1 > 0.f) ? s1 : SLOPE * s1;
      e0 = __expf(s0); e1 = __expf(s1);
    }
    dl0 += e0; dl1 += e1;
    ebuf0[wid][lane] = e0; ebuf1[wid][lane] = e1; sbuf[wid][lane] = s;
    __builtin_amdgcn_wave_barrier();
    int cend = end - c; if (cend > 64) cend = 64;
#pragma unroll 2
    for (int t = 0; t < cend; t += 2) {
      int th = t + half_;
      if (th < cend) {
        int st = sbuf[wid][th];
        float w = (hl < 16) ? ebuf0[wid][th] : ebuf1[wid][th];
        const __half2* p = (const __half2*)(xh + (size_t)st * F + hl * 4);
        __half2 u0 = p[0], u1 = p[1];
        float2 f0 = __half22float2(u0);
        float2 f1 = __half22float2(u1);
        acc[0] += w * f0.x; acc[1] += w * f0.y;
        acc[2] += w * f1.x; acc[3] += w * f1.y;
      }
    }
    __builtin_amdgcn_wave_barrier();
  }
#pragma unroll
  for (int off = 32; off > 0; off >>= 1) {
    dl0 += __shfl_xor(dl0, off, 64);
    dl1 += __shfl_xor(dl1, off, 64);
  }
#pragma unroll
  for (int q = 0; q < 4; ++q) acc[q] += __shfl_xor(acc[q], 32, 64);
  if (half_ == 0) {
    float d = (hl < 16) ? dl0 : dl1;
    float inv = 1.f / (d + EPS_DEN);
    float4 o;
    o.x = fmaxf(acc[0] * inv, 0.f);
    o.y = fmaxf(acc[1] * inv, 0.f);
    o.z = fmaxf(acc[2] * inv, 0.f);
    o.w = fmaxf(acc[3] * inv, 0.f);
    *(float4*)(out + (size_t)node * F + hl * 4) = o;
  }
}

// ---------------- combine post_mp weights: Wc = Wp2@Wp1 (no activation between!)
__global__ void combine_kernel(const float* __restrict__ Wp1, const float* __restrict__ bp1,
    const float* __restrict__ Wp2, const float* __restrict__ bp2,
    float* __restrict__ Wct, float* __restrict__ bc) {
  int idx = blockIdx.x * 256 + threadIdx.x;
  if (blockIdx.x < 20) {                 // 5120 Wc entries
    int o = idx >> 7, k = idx & 127;
    float s = 0.f;
#pragma unroll 8
    for (int j = 0; j < 64; ++j) s += Wp2[o * 64 + j] * Wp1[j * 128 + k];
    Wct[k * 48 + o] = s;
  } else if (threadIdx.x < OUT_DIM) {    // bc
    int o = threadIdx.x;
    float s = bp2[o];
    for (int j = 0; j < 64; ++j) s += Wp2[o * 64 + j] * bp1[j];
    bc[o] = s;
  }
}

// ---------------- post GEMM + log_softmax: out[n,40] = h[n,128]@Wc^T + bc ------
__global__ __launch_bounds__(256) void post_kernel(const float* __restrict__ h,
    const float* __restrict__ Wct_g, const float* __restrict__ bc,
    float* __restrict__ out, int n) {
  __shared__ float Wct[128 * 48];        // [k][o] padded to 48 → 24 KB
  __shared__ float hs[128 * 33];         // [node][kk] kk-chunk of 32, pad 33
  int tid = threadIdx.x;
#pragma unroll
  for (int r = 0; r < 24; ++r) {
    int i = tid + 256 * r;               // 0..6143
    Wct[i] = Wct_g[i];
  }
  int tx = tid & 7, ty = tid >> 3;
  int base = blockIdx.x * 128;
  float z[4][5] = {};
  for (int kc = 0; kc < 128; kc += 32) {
    __syncthreads();
#pragma unroll
    for (int r = 0; r < 16; ++r) {
      int i = tid + 256 * r;             // 0..4095
      int nd = i >> 5, kk = i & 31;
      int gn = base + nd;
      hs[nd * 33 + kk] = (gn < n) ? h[(size_t)gn * F + kc + kk] : 0.f;
    }
    __syncthreads();
#pragma unroll 8
    for (int kk = 0; kk < 32; ++kk) {
      float a[4], b[5];
#pragma unroll
      for (int i = 0; i < 4; ++i) a[i] = hs[(ty * 4 + i) * 33 + kk];
#pragma unroll
      for (int c = 0; c < 5; ++c) b[c] = Wct[(kc + kk) * 48 + tx * 5 + c];
#pragma unroll
      for (int i = 0; i < 4; ++i)
#pragma unroll
        for (int c = 0; c < 5; ++c) z[i][c] += a[i] * b[c];
    }
  }
  float bcv[5];
#pragma unroll
  for (int c = 0; c < 5; ++c) bcv[c] = bc[tx * 5 + c];
#pragma unroll
  for (int i = 0; i < 4; ++i) {
    int node = base + ty * 4 + i;
    if (node >= n) continue;
    float zc[5], m = -INFINITY;
#pragma unroll
    for (int c = 0; c < 5; ++c) { zc[c] = z[i][c] + bcv[c]; m = fmaxf(m, zc[c]); }
    m = fmaxf(m, __shfl_xor(m, 1, 64));
    m = fmaxf(m, __shfl_xor(m, 2, 64));
    m = fmaxf(m, __shfl_xor(m, 4, 64));
    float s = 0.f;
#pragma unroll
    for (int c = 0; c < 5; ++c) s += __expf(zc[c] - m);
    s += __shfl_xor(s, 1, 64);
    s += __shfl_xor(s, 2, 64);
    s += __shfl_xor(s, 4, 64);
    float ls = logf(s);
#pragma unroll
    for (int c = 0; c < 5; ++c)
      out[(size_t)node * OUT_DIM + tx * 5 + c] = zc[c] - m - ls;
  }
}

extern "C" void kernel_launch(void* const* d_in, const int* in_sizes, int n_in,
                              void* d_out, int out_size, void* d_ws, size_t ws_size,
                              hipStream_t stream) {
  const float* x   = (const float*)d_in[0];
  const int*   ei  = (const int*)d_in[1];
  const float* W1  = (const float*)d_in[2];
  const float* b1  = (const float*)d_in[3];
  const float* al1 = (const float*)d_in[4];
  const float* ar1 = (const float*)d_in[5];
  const float* W2  = (const float*)d_in[6];
  const float* b2  = (const float*)d_in[7];
  const float* al2 = (const float*)d_in[8];
  const float* ar2 = (const float*)d_in[9];
  const float* Wp1 = (const float*)d_in[10];
  const float* bp1 = (const float*)d_in[11];
  const float* Wp2 = (const float*)d_in[12];
  const float* bp2 = (const float*)d_in[13];
  float* out = (float*)d_out;

  float* bufB  = (float*)d_ws;                       // h fp32    [N,128]
  float* al    = bufB + (size_t)N_NODES * F;         // [N,2]
  float* ar    = al + (size_t)N_NODES * 2;           // [N,2]
  float* Wct   = ar + (size_t)N_NODES * 2;           // [128*48]
  float* bc    = Wct + 128 * 48;                     // [40]
  int*   cnt   = (int*)(bc + 64);                    // [N]
  int*   rowptr= cnt + N_NODES;                      // [N+1]
  int*   cursor= rowptr + N_NODES + 1;               // [N]
  int*   srcs  = cursor + N_NODES;                   // [E]
  __half* xh   = (__half*)(srcs + N_EDGES);          // xt fp16   [N,128]
  // scan scratch aliases (used only during CSR build, before al/srcs are live):
  int*   partial = srcs;                             // [N] into srcs
  int*   bsum    = (int*)al;                         // [64] into al

  const int SCAN_BLOCKS = (N_NODES + 1023) / 1024;   // 49

  // ---- CSR by destination (edge_index shared by both layers) ----
  hipMemsetAsync(cnt, 0, N_NODES * sizeof(int), stream);
  count_kernel<<<(N_EDGES + 255) / 256, 256, 0, stream>>>(ei, cnt);
  scan1_kernel<<<SCAN_BLOCKS, 1024, 0, stream>>>(cnt, partial, bsum, N_NODES);
  scan2_kernel<<<1, 64, 0, stream>>>(bsum, SCAN_BLOCKS);
  scan3_kernel<<<SCAN_BLOCKS, 1024, 0, stream>>>(partial, bsum, cnt, rowptr, cursor, N_NODES);
  fill_kernel<<<(N_EDGES + 255) / 256, 256, 0, stream>>>(ei, cursor, srcs);
  combine_kernel<<<21, 256, 0, stream>>>(Wp1, bp1, Wp2, bp2, Wct, bc);

  dim3 ggrid((N_NODES + 63) / 64, 2);
  int nwgrid = (N_NODES + 3) / 4;  // 4 node-waves per 256-thread block

  // ---- layer 1 ----
  gemm_xw_fp16<<<ggrid, 256, 0, stream>>>(x, W1, b1, xh, N_NODES);
  alphas_kernel<<<nwgrid, 256, 0, stream>>>(xh, al1, ar1, al, ar, N_NODES);
  aggregate_kernel<<<nwgrid, 256, 0, stream>>>(rowptr, srcs, al, ar, xh, bufB, N_NODES);
  // ---- layer 2 ----
  gemm_xw_fp16<<<ggrid, 256, 0, stream>>>(bufB, W2, b2, xh, N_NODES);
  alphas_kernel<<<nwgrid, 256, 0, stream>>>(xh, al2, ar2, al, ar, N_NODES);
  aggregate_kernel<<<nwgrid, 256, 0, stream>>>(rowptr, srcs, al, ar, xh, bufB, N_NODES);
  // ---- post_mp + log_softmax ----
  post_kernel<<<(N_NODES + 127) / 128, 256, 0, stream>>>(bufB, Wct, bc, out, N_NODES);
}

// Round 5
// 349.427 us; speedup vs baseline: 2.3693x; 1.1428x over previous
//
#include <hip/hip_runtime.h>
#include <hip/hip_fp16.h>
#include <cmath>

#define N_NODES 50000
#define N_EDGES 800000
#define F 128          // HEADS*HID
#define OUT_DIM 40
#define SLOPE 0.2f
#define EPS_DEN 1e-16f

#define BK_SHIFT 7
#define BKSZ 128                         // nodes per bucket
#define NBK ((N_NODES + BKSZ - 1) / BKSZ)  // 391
#define BK_CAP 3072                      // max edges/bucket (mean 2048, sigma 45)
#define SC_CHUNK 2500                    // edges per scatter/count block
#define SC_BLOCKS ((N_EDGES + SC_CHUNK - 1) / SC_CHUNK)  // 320

// ------- GEMM: Ch[n,128] = fp16( A[n,128] @ W[128,128]^T + b ), fp32 accumulate
__global__ __launch_bounds__(256) void gemm_xw_fp16(const float* __restrict__ A,
    const float* __restrict__ W, const float* __restrict__ b,
    __half* __restrict__ Ch, int nrows) {
  const int K = 128;
  __shared__ float Ast[32][68];   // [kk][row]
  __shared__ float Bst[32][68];   // [kk][col]
  int tid = threadIdx.x;
  int tx = tid & 15, ty = tid >> 4;
  int row0 = blockIdx.x * 64;
  int col0 = blockIdx.y * 64;
  float acc[4][4] = {};
  for (int kc = 0; kc < K; kc += 32) {
#pragma unroll
    for (int l = 0; l < 2; ++l) {
      int i = tid + 256 * l;        // 0..511
      int r = i >> 3, k4 = i & 7;   // r: 0..63, k4: 0..7
      int gr = row0 + r;
      float4 v = (gr < nrows) ? *(const float4*)(A + (size_t)gr * K + kc + k4 * 4)
                              : make_float4(0.f, 0.f, 0.f, 0.f);
      Ast[k4 * 4 + 0][r] = v.x; Ast[k4 * 4 + 1][r] = v.y;
      Ast[k4 * 4 + 2][r] = v.z; Ast[k4 * 4 + 3][r] = v.w;
      float4 w4 = *(const float4*)(W + (size_t)(col0 + r) * K + kc + k4 * 4);
      Bst[k4 * 4 + 0][r] = w4.x; Bst[k4 * 4 + 1][r] = w4.y;
      Bst[k4 * 4 + 2][r] = w4.z; Bst[k4 * 4 + 3][r] = w4.w;
    }
    __syncthreads();
#pragma unroll
    for (int kk = 0; kk < 32; ++kk) {
      float4 a4 = *(const float4*)&Ast[kk][ty * 4];
      float4 b4 = *(const float4*)&Bst[kk][tx * 4];
      float a[4] = {a4.x, a4.y, a4.z, a4.w};
      float bb[4] = {b4.x, b4.y, b4.z, b4.w};
#pragma unroll
      for (int i = 0; i < 4; ++i)
#pragma unroll
        for (int j = 0; j < 4; ++j) acc[i][j] += a[i] * bb[j];
    }
    __syncthreads();
  }
  int gc = col0 + tx * 4;
  float b0 = b[gc], b1v = b[gc + 1], b2v = b[gc + 2], b3 = b[gc + 3];
#pragma unroll
  for (int i = 0; i < 4; ++i) {
    int gr = row0 + ty * 4 + i;
    if (gr >= nrows) continue;
    __half2 h0 = __floats2half2_rn(acc[i][0] + b0, acc[i][1] + b1v);
    __half2 h1 = __floats2half2_rn(acc[i][2] + b2v, acc[i][3] + b3);
    __half2* dst = (__half2*)(Ch + (size_t)gr * K + gc);
    dst[0] = h0; dst[1] = h1;
  }
}

// ---------------- per-node attention coefficients (reads fp16 xt) --------------
__global__ __launch_bounds__(256) void alphas_kernel(const __half* __restrict__ xh,
    const float* __restrict__ attl, const float* __restrict__ attr,
    float* __restrict__ al, float* __restrict__ ar, int n) {
  int node = (int)((blockIdx.x * blockDim.x + threadIdx.x) >> 6);
  int lane = threadIdx.x & 63;
  if (node >= n) return;
  float v0 = __half2float(xh[(size_t)node * F + lane]);
  float v1 = __half2float(xh[(size_t)node * F + 64 + lane]);
  float2 wl = *(const float2*)(attl + lane * 2);
  float2 wr = *(const float2*)(attr + lane * 2);
  float l0 = v0 * wl.x;
  float r0 = v0 * wr.x;
  float l1 = v1 * wl.y;
  float r1 = v1 * wr.y;
#pragma unroll
  for (int off = 32; off > 0; off >>= 1) {
    l0 += __shfl_down(l0, off, 64);
    r0 += __shfl_down(r0, off, 64);
    l1 += __shfl_down(l1, off, 64);
    r1 += __shfl_down(r1, off, 64);
  }
  if (lane == 0) {
    al[node * 2 + 0] = l0; al[node * 2 + 1] = l1;
    ar[node * 2 + 0] = r0; ar[node * 2 + 1] = r1;
  }
}

// ============ CSR build via two-level bucket sort (all writes coalesced) =======
__global__ __launch_bounds__(256) void bucket_count(const int* __restrict__ ei,
                                                    int* __restrict__ bcnt) {
  __shared__ int h[NBK];
  int tid = threadIdx.x;
  for (int i = tid; i < NBK; i += 256) h[i] = 0;
  __syncthreads();
  int base = blockIdx.x * SC_CHUNK;
  int end = base + SC_CHUNK; if (end > N_EDGES) end = N_EDGES;
  for (int e = base + tid; e < end; e += 256)
    atomicAdd(&h[((unsigned)ei[N_EDGES + e]) >> BK_SHIFT], 1);
  __syncthreads();
  for (int i = tid; i < NBK; i += 256)
    if (h[i]) atomicAdd(&bcnt[i], h[i]);
}

__global__ void bucket_scan(const int* __restrict__ bcnt, int* __restrict__ bbase,
                            int* __restrict__ bcur, int* __restrict__ rowptr) {
  int lane = threadIdx.x;  // 64 threads
  int carry = 0;
  for (int c = 0; c < NBK; c += 64) {
    int i = c + lane;
    int v = (i < NBK) ? bcnt[i] : 0;
    int x = v;
#pragma unroll
    for (int off = 1; off < 64; off <<= 1) {
      int t = __shfl_up(x, off, 64);
      if (lane >= off) x += t;
    }
    int excl = carry + x - v;
    if (i < NBK) { bbase[i] = excl; bcur[i] = excl; }
    carry += __shfl(x, 63, 64);
  }
  if (lane == 0) { bbase[NBK] = carry; rowptr[N_NODES] = N_EDGES; }
}

// stage chunk in LDS, reserve contiguous per-bucket ranges, write packed ints
__global__ __launch_bounds__(256) void bucket_scatter(const int* __restrict__ ei,
    int* __restrict__ bcur, int* __restrict__ pairs) {
  __shared__ int   sd[SC_CHUNK];    // (src << 7) | (dst & 127)
  __shared__ short sb[SC_CHUNK];    // bucket id
  __shared__ int h[NBK], lofs[NBK];
  int tid = threadIdx.x;
  for (int i = tid; i < NBK; i += 256) h[i] = 0;
  __syncthreads();
  int base = blockIdx.x * SC_CHUNK;
  int end = base + SC_CHUNK; if (end > N_EDGES) end = N_EDGES;
  int cnt = end - base;
  for (int e = base + tid; e < end; e += 256) {
    int s = ei[e];
    int d = ei[N_EDGES + e];
    int b = d >> BK_SHIFT;
    sd[e - base] = (s << BK_SHIFT) | (d & (BKSZ - 1));
    sb[e - base] = (short)b;
    atomicAdd(&h[b], 1);
  }
  __syncthreads();
  for (int i = tid; i < NBK; i += 256)
    if (h[i]) { lofs[i] = atomicAdd(&bcur[i], h[i]); h[i] = 0; }
  __syncthreads();
  for (int i = tid; i < cnt; i += 256) {
    int b = sb[i];
    int pos = lofs[b] + atomicAdd(&h[b], 1);
    pairs[pos] = sd[i];
  }
}

// one block per bucket: exact sort by dst in LDS; emits rowptr + coalesced srcs
__global__ __launch_bounds__(256) void local_sort(const int* __restrict__ bbase,
    const int* __restrict__ pairs, int* __restrict__ rowptr, int* __restrict__ srcs) {
  __shared__ int buf[BK_CAP];
  __shared__ int sorted[BK_CAP];
  __shared__ int hist[BKSZ];
  __shared__ int cur[BKSZ];
  int tid = threadIdx.x;
  int b = blockIdx.x;
  int base = bbase[b];
  int cnt = bbase[b + 1] - base;
  if (cnt > BK_CAP) cnt = BK_CAP;   // statistically impossible; guards LDS
  if (tid < BKSZ) hist[tid] = 0;
  __syncthreads();
  for (int i = tid; i < cnt; i += 256) {
    int p = pairs[base + i];
    buf[i] = p;
    atomicAdd(&hist[p & (BKSZ - 1)], 1);
  }
  __syncthreads();
  if (tid < 64) {
    int lane = tid;
    int carry = 0;
#pragma unroll
    for (int c = 0; c < BKSZ; c += 64) {
      int v = hist[c + lane];
      int x = v;
#pragma unroll
      for (int off = 1; off < 64; off <<= 1) {
        int t = __shfl_up(x, off, 64);
        if (lane >= off) x += t;
      }
      int excl = carry + x - v;
      cur[c + lane] = excl;
      int node = b * BKSZ + c + lane;
      if (node < N_NODES) rowptr[node] = base + excl;
      carry += __shfl(x, 63, 64);
    }
  }
  __syncthreads();
  for (int i = tid; i < cnt; i += 256) {
    int p = buf[i];
    int pos = atomicAdd(&cur[p & (BKSZ - 1)], 1);
    sorted[pos] = p >> BK_SHIFT;
  }
  __syncthreads();
  for (int i = tid; i < cnt; i += 256)
    srcs[base + i] = sorted[i];
}

// ---------------- fused GAT aggregation: one wave per destination node ----------
__global__ __launch_bounds__(256) void aggregate_kernel(const int* __restrict__ rowptr,
    const int* __restrict__ srcs, const float* __restrict__ al, const float* __restrict__ ar,
    const __half* __restrict__ xh, float* __restrict__ out, int n) {
  __shared__ float ebuf0[4][64];
  __shared__ float ebuf1[4][64];
  __shared__ int   sbuf[4][64];
  int tid = threadIdx.x;
  int wid = tid >> 6, lane = tid & 63;
  int half_ = lane >> 5, hl = lane & 31;
  int node = blockIdx.x * 4 + wid;
  if (node >= n) return;
  int start = rowptr[node], end = rowptr[node + 1];
  float2 arv = *(const float2*)(ar + (size_t)node * 2);
  float ar0 = arv.x, ar1 = arv.y;
  float acc[4] = {0.f, 0.f, 0.f, 0.f};
  float dl0 = 0.f, dl1 = 0.f;
  for (int c = start; c < end; c += 64) {
    int j = c + lane;
    float e0 = 0.f, e1 = 0.f; int s = 0;
    if (j < end) {
      s = srcs[j];
      float2 a = *(const float2*)(al + (size_t)s * 2);
      float s0 = a.x + ar0; s0 = (s0 > 0.f) ? s0 : SLOPE * s0;
      float s1 = a.y + ar1; s1 = (s1 > 0.f) ? s1 : SLOPE * s1;
      e0 = __expf(s0); e1 = __expf(s1);
    }
    dl0 += e0; dl1 += e1;
    ebuf0[wid][lane] = e0; ebuf1[wid][lane] = e1; sbuf[wid][lane] = s;
    __builtin_amdgcn_wave_barrier();
    int cend = end - c; if (cend > 64) cend = 64;
#pragma unroll 2
    for (int t = 0; t < cend; t += 2) {
      int th = t + half_;
      if (th < cend) {
        int st = sbuf[wid][th];
        float w = (hl < 16) ? ebuf0[wid][th] : ebuf1[wid][th];
        const __half2* p = (const __half2*)(xh + (size_t)st * F + hl * 4);
        __half2 u0 = p[0], u1 = p[1];
        float2 f0 = __half22float2(u0);
        float2 f1 = __half22float2(u1);
        acc[0] += w * f0.x; acc[1] += w * f0.y;
        acc[2] += w * f1.x; acc[3] += w * f1.y;
      }
    }
    __builtin_amdgcn_wave_barrier();
  }
#pragma unroll
  for (int off = 32; off > 0; off >>= 1) {
    dl0 += __shfl_xor(dl0, off, 64);
    dl1 += __shfl_xor(dl1, off, 64);
  }
#pragma unroll
  for (int q = 0; q < 4; ++q) acc[q] += __shfl_xor(acc[q], 32, 64);
  if (half_ == 0) {
    float d = (hl < 16) ? dl0 : dl1;
    float inv = 1.f / (d + EPS_DEN);
    float4 o;
    o.x = fmaxf(acc[0] * inv, 0.f);
    o.y = fmaxf(acc[1] * inv, 0.f);
    o.z = fmaxf(acc[2] * inv, 0.f);
    o.w = fmaxf(acc[3] * inv, 0.f);
    *(float4*)(out + (size_t)node * F + hl * 4) = o;
  }
}

// ---------------- combine post_mp weights: Wc = Wp2@Wp1 (no activation between!)
__global__ void combine_kernel(const float* __restrict__ Wp1, const float* __restrict__ bp1,
    const float* __restrict__ Wp2, const float* __restrict__ bp2,
    float* __restrict__ Wct, float* __restrict__ bc) {
  int idx = blockIdx.x * 256 + threadIdx.x;
  if (blockIdx.x < 20) {                 // 5120 Wc entries
    int o = idx >> 7, k = idx & 127;
    float s = 0.f;
#pragma unroll 8
    for (int j = 0; j < 64; ++j) s += Wp2[o * 64 + j] * Wp1[j * 128 + k];
    Wct[k * 48 + o] = s;
  } else if (threadIdx.x < OUT_DIM) {    // bc
    int o = threadIdx.x;
    float s = bp2[o];
    for (int j = 0; j < 64; ++j) s += Wp2[o * 64 + j] * bp1[j];
    bc[o] = s;
  }
}

// ---------------- post GEMM + log_softmax: out[n,40] = h[n,128]@Wc^T + bc ------
__global__ __launch_bounds__(256) void post_kernel(const float* __restrict__ h,
    const float* __restrict__ Wct_g, const float* __restrict__ bc,
    float* __restrict__ out, int n) {
  __shared__ float Wct[128 * 48];        // [k][o] padded to 48 → 24 KB
  __shared__ float hs[128 * 33];         // [node][kk] kk-chunk of 32, pad 33
  int tid = threadIdx.x;
#pragma unroll
  for (int r = 0; r < 24; ++r) {
    int i = tid + 256 * r;               // 0..6143
    Wct[i] = Wct_g[i];
  }
  int tx = tid & 7, ty = tid >> 3;
  int base = blockIdx.x * 128;
  float z[4][5] = {};
  for (int kc = 0; kc < 128; kc += 32) {
    __syncthreads();
#pragma unroll
    for (int r = 0; r < 16; ++r) {
      int i = tid + 256 * r;             // 0..4095
      int nd = i >> 5, kk = i & 31;
      int gn = base + nd;
      hs[nd * 33 + kk] = (gn < n) ? h[(size_t)gn * F + kc + kk] : 0.f;
    }
    __syncthreads();
#pragma unroll 8
    for (int kk = 0; kk < 32; ++kk) {
      float a[4], b[5];
#pragma unroll
      for (int i = 0; i < 4; ++i) a[i] = hs[(ty * 4 + i) * 33 + kk];
#pragma unroll
      for (int c = 0; c < 5; ++c) b[c] = Wct[(kc + kk) * 48 + tx * 5 + c];
#pragma unroll
      for (int i = 0; i < 4; ++i)
#pragma unroll
        for (int c = 0; c < 5; ++c) z[i][c] += a[i] * b[c];
    }
  }
  float bcv[5];
#pragma unroll
  for (int c = 0; c < 5; ++c) bcv[c] = bc[tx * 5 + c];
#pragma unroll
  for (int i = 0; i < 4; ++i) {
    int node = base + ty * 4 + i;
    if (node >= n) continue;
    float zc[5], m = -INFINITY;
#pragma unroll
    for (int c = 0; c < 5; ++c) { zc[c] = z[i][c] + bcv[c]; m = fmaxf(m, zc[c]); }
    m = fmaxf(m, __shfl_xor(m, 1, 64));
    m = fmaxf(m, __shfl_xor(m, 2, 64));
    m = fmaxf(m, __shfl_xor(m, 4, 64));
    float s = 0.f;
#pragma unroll
    for (int c = 0; c < 5; ++c) s += __expf(zc[c] - m);
    s += __shfl_xor(s, 1, 64);
    s += __shfl_xor(s, 2, 64);
    s += __shfl_xor(s, 4, 64);
    float ls = logf(s);
#pragma unroll
    for (int c = 0; c < 5; ++c)
      out[(size_t)node * OUT_DIM + tx * 5 + c] = zc[c] - m - ls;
  }
}

extern "C" void kernel_launch(void* const* d_in, const int* in_sizes, int n_in,
                              void* d_out, int out_size, void* d_ws, size_t ws_size,
                              hipStream_t stream) {
  const float* x   = (const float*)d_in[0];
  const int*   ei  = (const int*)d_in[1];
  const float* W1  = (const float*)d_in[2];
  const float* b1  = (const float*)d_in[3];
  const float* al1 = (const float*)d_in[4];
  const float* ar1 = (const float*)d_in[5];
  const float* W2  = (const float*)d_in[6];
  const float* b2  = (const float*)d_in[7];
  const float* al2 = (const float*)d_in[8];
  const float* ar2 = (const float*)d_in[9];
  const float* Wp1 = (const float*)d_in[10];
  const float* bp1 = (const float*)d_in[11];
  const float* Wp2 = (const float*)d_in[12];
  const float* bp2 = (const float*)d_in[13];
  float* out = (float*)d_out;

  float* bufB  = (float*)d_ws;                       // h fp32    [N,128]
  float* al    = bufB + (size_t)N_NODES * F;         // [N,2]
  float* ar    = al + (size_t)N_NODES * 2;           // [N,2]
  float* Wct   = ar + (size_t)N_NODES * 2;           // [128*48]
  float* bc    = Wct + 128 * 48;                     // [40]
  int*   rowptr= (int*)(bc + 64);                    // [N+1]
  int*   srcs  = rowptr + N_NODES + 1;               // [E]
  int*   pairs = srcs + N_EDGES;                     // [E]
  int*   bcnt  = pairs + N_EDGES;                    // [NBK]
  int*   bbase = bcnt + NBK;                         // [NBK+1]
  int*   bcur  = bbase + NBK + 1;                    // [NBK]
  __half* xh   = (__half*)(bcur + NBK);              // xt fp16   [N,128]

  // ---- CSR by destination via bucket sort (edge_index shared by both layers) --
  hipMemsetAsync(bcnt, 0, NBK * sizeof(int), stream);
  bucket_count<<<SC_BLOCKS, 256, 0, stream>>>(ei, bcnt);
  bucket_scan<<<1, 64, 0, stream>>>(bcnt, bbase, bcur, rowptr);
  bucket_scatter<<<SC_BLOCKS, 256, 0, stream>>>(ei, bcur, pairs);
  local_sort<<<NBK, 256, 0, stream>>>(bbase, pairs, rowptr, srcs);
  combine_kernel<<<21, 256, 0, stream>>>(Wp1, bp1, Wp2, bp2, Wct, bc);

  dim3 ggrid((N_NODES + 63) / 64, 2);
  int nwgrid = (N_NODES + 3) / 4;  // 4 node-waves per 256-thread block

  // ---- layer 1 ----
  gemm_xw_fp16<<<ggrid, 256, 0, stream>>>(x, W1, b1, xh, N_NODES);
  alphas_kernel<<<nwgrid, 256, 0, stream>>>(xh, al1, ar1, al, ar, N_NODES);
  aggregate_kernel<<<nwgrid, 256, 0, stream>>>(rowptr, srcs, al, ar, xh, bufB, N_NODES);
  // ---- layer 2 ----
  gemm_xw_fp16<<<ggrid, 256, 0, stream>>>(bufB, W2, b2, xh, N_NODES);
  alphas_kernel<<<nwgrid, 256, 0, stream>>>(xh, al2, ar2, al, ar, N_NODES);
  aggregate_kernel<<<nwgrid, 256, 0, stream>>>(rowptr, srcs, al, ar, xh, bufB, N_NODES);
  // ---- post_mp + log_softmax ----
  post_kernel<<<(N_NODES + 127) / 128, 256, 0, stream>>>(bufB, Wct, bc, out, N_NODES);
}

// Round 6
// 317.523 us; speedup vs baseline: 2.6074x; 1.1005x over previous
//
#include <hip/hip_runtime.h>
#include <hip/hip_fp16.h>
#include <cmath>

#define N_NODES 50000
#define N_EDGES 800000
#define F 128          // HEADS*HID
#define OUT_DIM 40
#define SLOPE 0.2f
#define EPS_DEN 1e-16f

#define BK_SHIFT 7
#define BKSZ 128                         // nodes per bucket
#define NBK ((N_NODES + BKSZ - 1) / BKSZ)  // 391
#define BK_CAP 3072                      // max edges/bucket (mean 2048, sigma 45)
#define SC_CHUNK 2500                    // edges per scatter/count block
#define SC_BLOCKS ((N_EDGES + SC_CHUNK - 1) / SC_CHUNK)  // 320

// ---- staging loaders: 4 consecutive elements as float4 ----
__device__ inline float4 load4(const float* p) { return *(const float4*)p; }
__device__ inline float4 load4(const __half* p) {
  uint2 u = *(const uint2*)p;
  float2 a = __half22float2(*(__half2*)&u.x);
  float2 b = __half22float2(*(__half2*)&u.y);
  return make_float4(a.x, a.y, b.x, b.y);
}

// ------- GEMM: Ch[n,128] = fp16( A[n,128] @ W[128,128]^T + b ), fp32 accumulate.
// Fused alpha epilogue: head h == blockIdx.y owns cols h*64..h*64+63 entirely, so
// al[n,h] = sum_c (acc+bias)*attl[c,h] reduces across the 16 tx lanes (contiguous,
// 16-aligned within a wave) with shfl_xor 1/2/4/8.
template <typename T>
__global__ __launch_bounds__(256) void gemm_fused(const T* __restrict__ A,
    const float* __restrict__ W, const float* __restrict__ b,
    const float* __restrict__ attl, const float* __restrict__ attr,
    __half* __restrict__ Ch, float* __restrict__ al, float* __restrict__ ar,
    int nrows) {
  const int K = 128;
  __shared__ float Ast[32][68];   // [kk][row]
  __shared__ float Bst[32][68];   // [kk][col]
  int tid = threadIdx.x;
  int tx = tid & 15, ty = tid >> 4;
  int row0 = blockIdx.x * 64;
  int col0 = blockIdx.y * 64;
  float acc[4][4] = {};
  for (int kc = 0; kc < K; kc += 32) {
#pragma unroll
    for (int l = 0; l < 2; ++l) {
      int i = tid + 256 * l;        // 0..511
      int r = i >> 3, k4 = i & 7;   // r: 0..63, k4: 0..7
      int gr = row0 + r;
      float4 v = (gr < nrows) ? load4(A + (size_t)gr * K + kc + k4 * 4)
                              : make_float4(0.f, 0.f, 0.f, 0.f);
      Ast[k4 * 4 + 0][r] = v.x; Ast[k4 * 4 + 1][r] = v.y;
      Ast[k4 * 4 + 2][r] = v.z; Ast[k4 * 4 + 3][r] = v.w;
      float4 w4 = *(const float4*)(W + (size_t)(col0 + r) * K + kc + k4 * 4);
      Bst[k4 * 4 + 0][r] = w4.x; Bst[k4 * 4 + 1][r] = w4.y;
      Bst[k4 * 4 + 2][r] = w4.z; Bst[k4 * 4 + 3][r] = w4.w;
    }
    __syncthreads();
#pragma unroll
    for (int kk = 0; kk < 32; ++kk) {
      float4 a4 = *(const float4*)&Ast[kk][ty * 4];
      float4 b4 = *(const float4*)&Bst[kk][tx * 4];
      float a[4] = {a4.x, a4.y, a4.z, a4.w};
      float bb[4] = {b4.x, b4.y, b4.z, b4.w};
#pragma unroll
      for (int i = 0; i < 4; ++i)
#pragma unroll
        for (int j = 0; j < 4; ++j) acc[i][j] += a[i] * bb[j];
    }
    __syncthreads();
  }
  int head = blockIdx.y;
  int gc = col0 + tx * 4;
  float bj[4], wl4[4], wr4[4];
#pragma unroll
  for (int j = 0; j < 4; ++j) {
    bj[j] = b[gc + j];
    int c = tx * 4 + j;                  // col within head
    wl4[j] = attl[c * 2 + head];
    wr4[j] = attr[c * 2 + head];
  }
#pragma unroll
  for (int i = 0; i < 4; ++i)
#pragma unroll
    for (int j = 0; j < 4; ++j) acc[i][j] += bj[j];
#pragma unroll
  for (int i = 0; i < 4; ++i) {
    int gr = row0 + ty * 4 + i;
    // alpha partial dots + 16-lane reduction
    float pl = 0.f, pr = 0.f;
#pragma unroll
    for (int j = 0; j < 4; ++j) { pl += acc[i][j] * wl4[j]; pr += acc[i][j] * wr4[j]; }
    pl += __shfl_xor(pl, 1, 64); pr += __shfl_xor(pr, 1, 64);
    pl += __shfl_xor(pl, 2, 64); pr += __shfl_xor(pr, 2, 64);
    pl += __shfl_xor(pl, 4, 64); pr += __shfl_xor(pr, 4, 64);
    pl += __shfl_xor(pl, 8, 64); pr += __shfl_xor(pr, 8, 64);
    if (gr < nrows) {
      __half2 h0 = __floats2half2_rn(acc[i][0], acc[i][1]);
      __half2 h1 = __floats2half2_rn(acc[i][2], acc[i][3]);
      __half2* dst = (__half2*)(Ch + (size_t)gr * K + gc);
      dst[0] = h0; dst[1] = h1;
      if (tx == 0) { al[gr * 2 + head] = pl; ar[gr * 2 + head] = pr; }
    }
  }
}

// ============ CSR build via two-level bucket sort (all writes coalesced) =======
__global__ __launch_bounds__(256) void bucket_count(const int* __restrict__ ei,
                                                    int* __restrict__ bcnt) {
  __shared__ int h[NBK];
  int tid = threadIdx.x;
  for (int i = tid; i < NBK; i += 256) h[i] = 0;
  __syncthreads();
  int base = blockIdx.x * SC_CHUNK;
  int end = base + SC_CHUNK; if (end > N_EDGES) end = N_EDGES;
  for (int e = base + tid; e < end; e += 256)
    atomicAdd(&h[((unsigned)ei[N_EDGES + e]) >> BK_SHIFT], 1);
  __syncthreads();
  for (int i = tid; i < NBK; i += 256)
    if (h[i]) atomicAdd(&bcnt[i], h[i]);
}

__global__ void bucket_scan(const int* __restrict__ bcnt, int* __restrict__ bbase,
                            int* __restrict__ bcur, int* __restrict__ rowptr) {
  int lane = threadIdx.x;  // 64 threads
  int carry = 0;
  for (int c = 0; c < NBK; c += 64) {
    int i = c + lane;
    int v = (i < NBK) ? bcnt[i] : 0;
    int x = v;
#pragma unroll
    for (int off = 1; off < 64; off <<= 1) {
      int t = __shfl_up(x, off, 64);
      if (lane >= off) x += t;
    }
    int excl = carry + x - v;
    if (i < NBK) { bbase[i] = excl; bcur[i] = excl; }
    carry += __shfl(x, 63, 64);
  }
  if (lane == 0) { bbase[NBK] = carry; rowptr[N_NODES] = N_EDGES; }
}

__global__ __launch_bounds__(256) void bucket_scatter(const int* __restrict__ ei,
    int* __restrict__ bcur, int* __restrict__ pairs) {
  __shared__ int   sd[SC_CHUNK];    // (src << 7) | (dst & 127)
  __shared__ short sb[SC_CHUNK];    // bucket id
  __shared__ int h[NBK], lofs[NBK];
  int tid = threadIdx.x;
  for (int i = tid; i < NBK; i += 256) h[i] = 0;
  __syncthreads();
  int base = blockIdx.x * SC_CHUNK;
  int end = base + SC_CHUNK; if (end > N_EDGES) end = N_EDGES;
  int cnt = end - base;
  for (int e = base + tid; e < end; e += 256) {
    int s = ei[e];
    int d = ei[N_EDGES + e];
    int b = d >> BK_SHIFT;
    sd[e - base] = (s << BK_SHIFT) | (d & (BKSZ - 1));
    sb[e - base] = (short)b;
    atomicAdd(&h[b], 1);
  }
  __syncthreads();
  for (int i = tid; i < NBK; i += 256)
    if (h[i]) { lofs[i] = atomicAdd(&bcur[i], h[i]); h[i] = 0; }
  __syncthreads();
  for (int i = tid; i < cnt; i += 256) {
    int b = sb[i];
    int pos = lofs[b] + atomicAdd(&h[b], 1);
    pairs[pos] = sd[i];
  }
}

__global__ __launch_bounds__(256) void local_sort(const int* __restrict__ bbase,
    const int* __restrict__ pairs, int* __restrict__ rowptr, int* __restrict__ srcs) {
  __shared__ int buf[BK_CAP];
  __shared__ int sorted[BK_CAP];
  __shared__ int hist[BKSZ];
  __shared__ int cur[BKSZ];
  int tid = threadIdx.x;
  int b = blockIdx.x;
  int base = bbase[b];
  int cnt = bbase[b + 1] - base;
  if (cnt > BK_CAP) cnt = BK_CAP;   // statistically impossible; guards LDS
  if (tid < BKSZ) hist[tid] = 0;
  __syncthreads();
  for (int i = tid; i < cnt; i += 256) {
    int p = pairs[base + i];
    buf[i] = p;
    atomicAdd(&hist[p & (BKSZ - 1)], 1);
  }
  __syncthreads();
  if (tid < 64) {
    int lane = tid;
    int carry = 0;
#pragma unroll
    for (int c = 0; c < BKSZ; c += 64) {
      int v = hist[c + lane];
      int x = v;
#pragma unroll
      for (int off = 1; off < 64; off <<= 1) {
        int t = __shfl_up(x, off, 64);
        if (lane >= off) x += t;
      }
      int excl = carry + x - v;
      cur[c + lane] = excl;
      int node = b * BKSZ + c + lane;
      if (node < N_NODES) rowptr[node] = base + excl;
      carry += __shfl(x, 63, 64);
    }
  }
  __syncthreads();
  for (int i = tid; i < cnt; i += 256) {
    int p = buf[i];
    int pos = atomicAdd(&cur[p & (BKSZ - 1)], 1);
    sorted[pos] = p >> BK_SHIFT;
  }
  __syncthreads();
  for (int i = tid; i < cnt; i += 256)
    srcs[base + i] = sorted[i];
}

// ---------------- fused GAT aggregation: one wave per destination node ----------
// Edge pairs: lanes 0-31 gather edge t's 256B fp16 row (8B uint2/lane), lanes
// 32-63 edge t+1. Weight pointer & row base precomputed per lane; unroll 4 keeps
// ~8 loads in flight. Output written fp16.
__global__ __launch_bounds__(256) void aggregate_kernel(const int* __restrict__ rowptr,
    const int* __restrict__ srcs, const float* __restrict__ al, const float* __restrict__ ar,
    const __half* __restrict__ xh, __half* __restrict__ out, int n) {
  __shared__ float ebuf[4][2][64];
  __shared__ int   sbuf[4][64];
  int tid = threadIdx.x;
  int wid = tid >> 6, lane = tid & 63;
  int half_ = lane >> 5, hl = lane & 31;
  int node = blockIdx.x * 4 + wid;
  if (node >= n) return;
  int start = rowptr[node], end = rowptr[node + 1];
  float2 arv = *(const float2*)(ar + (size_t)node * 2);
  float ar0 = arv.x, ar1 = arv.y;
  const float* wrow = &ebuf[wid][hl >> 4][0];   // hl<16 → head0 weights
  const __half* xbase = xh + hl * 4;
  float acc[4] = {0.f, 0.f, 0.f, 0.f};
  float dl0 = 0.f, dl1 = 0.f;
  for (int c = start; c < end; c += 64) {
    int j = c + lane;
    float e0 = 0.f, e1 = 0.f; int soff = 0;
    if (j < end) {
      int s = srcs[j];
      soff = s << BK_SHIFT;               // s * F
      float2 a = *(const float2*)(al + (size_t)s * 2);
      float s0 = a.x + ar0; s0 = (s0 > 0.f) ? s0 : SLOPE * s0;
      float s1 = a.y + ar1; s1 = (s1 > 0.f) ? s1 : SLOPE * s1;
      e0 = __expf(s0); e1 = __expf(s1);
    }
    dl0 += e0; dl1 += e1;
    ebuf[wid][0][lane] = e0; ebuf[wid][1][lane] = e1; sbuf[wid][lane] = soff;
    __builtin_amdgcn_wave_barrier();
    int cend = end - c; if (cend > 64) cend = 64;
#pragma unroll 4
    for (int t = 0; t < cend; t += 2) {
      int th = t + half_;
      if (th < cend) {
        int so = sbuf[wid][th];
        float w = wrow[th];
        uint2 u = *(const uint2*)(xbase + so);
        float2 f0 = __half22float2(*(__half2*)&u.x);
        float2 f1 = __half22float2(*(__half2*)&u.y);
        acc[0] += w * f0.x; acc[1] += w * f0.y;
        acc[2] += w * f1.x; acc[3] += w * f1.y;
      }
    }
    __builtin_amdgcn_wave_barrier();
  }
#pragma unroll
  for (int off = 32; off > 0; off >>= 1) {
    dl0 += __shfl_xor(dl0, off, 64);
    dl1 += __shfl_xor(dl1, off, 64);
  }
#pragma unroll
  for (int q = 0; q < 4; ++q) acc[q] += __shfl_xor(acc[q], 32, 64);
  if (half_ == 0) {
    float d = (hl < 16) ? dl0 : dl1;
    float inv = 1.f / (d + EPS_DEN);
    __half2 o0 = __floats2half2_rn(fmaxf(acc[0] * inv, 0.f), fmaxf(acc[1] * inv, 0.f));
    __half2 o1 = __floats2half2_rn(fmaxf(acc[2] * inv, 0.f), fmaxf(acc[3] * inv, 0.f));
    uint2 pack;
    pack.x = *(unsigned*)&o0; pack.y = *(unsigned*)&o1;
    *(uint2*)(out + (size_t)node * F + hl * 4) = pack;
  }
}

// ---------------- combine post_mp weights: Wc = Wp2@Wp1 (no activation between!)
__global__ void combine_kernel(const float* __restrict__ Wp1, const float* __restrict__ bp1,
    const float* __restrict__ Wp2, const float* __restrict__ bp2,
    float* __restrict__ Wct, float* __restrict__ bc) {
  int idx = blockIdx.x * 256 + threadIdx.x;
  if (blockIdx.x < 20) {                 // 5120 Wc entries
    int o = idx >> 7, k = idx & 127;
    float s = 0.f;
#pragma unroll 8
    for (int j = 0; j < 64; ++j) s += Wp2[o * 64 + j] * Wp1[j * 128 + k];
    Wct[k * 48 + o] = s;
  } else if (threadIdx.x < OUT_DIM) {    // bc
    int o = threadIdx.x;
    float s = bp2[o];
    for (int j = 0; j < 64; ++j) s += Wp2[o * 64 + j] * bp1[j];
    bc[o] = s;
  }
}

// ---------------- post GEMM + log_softmax: out[n,40] = h[n,128]@Wc^T + bc ------
__global__ __launch_bounds__(256) void post_kernel(const __half* __restrict__ h,
    const float* __restrict__ Wct_g, const float* __restrict__ bc,
    float* __restrict__ out, int n) {
  __shared__ float Wct[128 * 48];        // [k][o] padded to 48 → 24 KB
  __shared__ float hs[128 * 33];         // [node][kk] kk-chunk of 32, pad 33
  int tid = threadIdx.x;
#pragma unroll
  for (int r = 0; r < 24; ++r) {
    int i = tid + 256 * r;               // 0..6143
    Wct[i] = Wct_g[i];
  }
  int tx = tid & 7, ty = tid >> 3;
  int base = blockIdx.x * 128;
  float z[4][5] = {};
  for (int kc = 0; kc < 128; kc += 32) {
    __syncthreads();
#pragma unroll
    for (int r = 0; r < 16; ++r) {
      int i = tid + 256 * r;             // 0..4095
      int nd = i >> 5, kk = i & 31;
      int gn = base + nd;
      hs[nd * 33 + kk] = (gn < n) ? __half2float(h[(size_t)gn * F + kc + kk]) : 0.f;
    }
    __syncthreads();
#pragma unroll 8
    for (int kk = 0; kk < 32; ++kk) {
      float a[4], b[5];
#pragma unroll
      for (int i = 0; i < 4; ++i) a[i] = hs[(ty * 4 + i) * 33 + kk];
#pragma unroll
      for (int c = 0; c < 5; ++c) b[c] = Wct[(kc + kk) * 48 + tx * 5 + c];
#pragma unroll
      for (int i = 0; i < 4; ++i)
#pragma unroll
        for (int c = 0; c < 5; ++c) z[i][c] += a[i] * b[c];
    }
  }
  float bcv[5];
#pragma unroll
  for (int c = 0; c < 5; ++c) bcv[c] = bc[tx * 5 + c];
#pragma unroll
  for (int i = 0; i < 4; ++i) {
    int node = base + ty * 4 + i;
    if (node >= n) continue;
    float zc[5], m = -INFINITY;
#pragma unroll
    for (int c = 0; c < 5; ++c) { zc[c] = z[i][c] + bcv[c]; m = fmaxf(m, zc[c]); }
    m = fmaxf(m, __shfl_xor(m, 1, 64));
    m = fmaxf(m, __shfl_xor(m, 2, 64));
    m = fmaxf(m, __shfl_xor(m, 4, 64));
    float s = 0.f;
#pragma unroll
    for (int c = 0; c < 5; ++c) s += __expf(zc[c] - m);
    s += __shfl_xor(s, 1, 64);
    s += __shfl_xor(s, 2, 64);
    s += __shfl_xor(s, 4, 64);
    float ls = logf(s);
#pragma unroll
    for (int c = 0; c < 5; ++c)
      out[(size_t)node * OUT_DIM + tx * 5 + c] = zc[c] - m - ls;
  }
}

extern "C" void kernel_launch(void* const* d_in, const int* in_sizes, int n_in,
                              void* d_out, int out_size, void* d_ws, size_t ws_size,
                              hipStream_t stream) {
  const float* x   = (const float*)d_in[0];
  const int*   ei  = (const int*)d_in[1];
  const float* W1  = (const float*)d_in[2];
  const float* b1  = (const float*)d_in[3];
  const float* al1 = (const float*)d_in[4];
  const float* ar1 = (const float*)d_in[5];
  const float* W2  = (const float*)d_in[6];
  const float* b2  = (const float*)d_in[7];
  const float* al2 = (const float*)d_in[8];
  const float* ar2 = (const float*)d_in[9];
  const float* Wp1 = (const float*)d_in[10];
  const float* bp1 = (const float*)d_in[11];
  const float* Wp2 = (const float*)d_in[12];
  const float* bp2 = (const float*)d_in[13];
  float* out = (float*)d_out;

  float* al    = (float*)d_ws;                       // [N,2]
  float* ar    = al + (size_t)N_NODES * 2;           // [N,2]
  float* Wct   = ar + (size_t)N_NODES * 2;           // [128*48]
  float* bc    = Wct + 128 * 48;                     // [40] (pad to 64)
  int*   rowptr= (int*)(bc + 64);                    // [N+1]
  int*   srcs  = rowptr + N_NODES + 1;               // [E]
  int*   pairs = srcs + N_EDGES;                     // [E]
  int*   bcnt  = pairs + N_EDGES;                    // [NBK]
  int*   bbase = bcnt + NBK;                         // [NBK+1]
  int*   bcur  = bbase + NBK + 1;                    // [NBK]
  uintptr_t pp = ((uintptr_t)(bcur + NBK) + 255) & ~(uintptr_t)255;
  __half* xh   = (__half*)pp;                        // xt fp16   [N,128]
  __half* hb   = xh + (size_t)N_NODES * F;           // h  fp16   [N,128]

  // ---- CSR by destination via bucket sort (edge_index shared by both layers) --
  hipMemsetAsync(bcnt, 0, NBK * sizeof(int), stream);
  bucket_count<<<SC_BLOCKS, 256, 0, stream>>>(ei, bcnt);
  bucket_scan<<<1, 64, 0, stream>>>(bcnt, bbase, bcur, rowptr);
  bucket_scatter<<<SC_BLOCKS, 256, 0, stream>>>(ei, bcur, pairs);
  local_sort<<<NBK, 256, 0, stream>>>(bbase, pairs, rowptr, srcs);
  combine_kernel<<<21, 256, 0, stream>>>(Wp1, bp1, Wp2, bp2, Wct, bc);

  dim3 ggrid((N_NODES + 63) / 64, 2);
  int nwgrid = (N_NODES + 3) / 4;  // 4 node-waves per 256-thread block

  // ---- layer 1 ----
  gemm_fused<float><<<ggrid, 256, 0, stream>>>(x, W1, b1, al1, ar1, xh, al, ar, N_NODES);
  aggregate_kernel<<<nwgrid, 256, 0, stream>>>(rowptr, srcs, al, ar, xh, hb, N_NODES);
  // ---- layer 2 ----
  gemm_fused<__half><<<ggrid, 256, 0, stream>>>(hb, W2, b2, al2, ar2, xh, al, ar, N_NODES);
  aggregate_kernel<<<nwgrid, 256, 0, stream>>>(rowptr, srcs, al, ar, xh, hb, N_NODES);
  // ---- post_mp + log_softmax ----
  post_kernel<<<(N_NODES + 127) / 128, 256, 0, stream>>>(hb, Wct, bc, out, N_NODES);
}

// Round 7
// 271.739 us; speedup vs baseline: 3.0467x; 1.1685x over previous
//
#include <hip/hip_runtime.h>
#include <hip/hip_fp16.h>
#include <cmath>

#define N_NODES 50000
#define N_EDGES 800000
#define F 128          // HEADS*HID
#define OUT_DIM 40
#define SLOPE 0.2f
#define EPS_DEN 1e-16f

#define BK_SHIFT 7
#define BKSZ 128                         // nodes per bucket
#define NBK ((N_NODES + BKSZ - 1) / BKSZ)  // 391
#define BK_CAP 3072                      // max edges/bucket (mean 2048, sigma 45)
#define SC_CHUNK 2500                    // edges per scatter/count block
#define SC_BLOCKS ((N_EDGES + SC_CHUNK - 1) / SC_CHUNK)  // 320

typedef _Float16 half8 __attribute__((ext_vector_type(8)));
typedef float floatx4 __attribute__((ext_vector_type(4)));

// ---- staging loaders: 4 consecutive elements as float4 ----
__device__ inline float4 load4(const float* p) { return *(const float4*)p; }
__device__ inline float4 load4(const __half* p) {
  uint2 u = *(const uint2*)p;
  float2 a = __half22float2(*(__half2*)&u.x);
  float2 b = __half22float2(*(__half2*)&u.y);
  return make_float4(a.x, a.y, b.x, b.y);
}

// ------- MFMA GEMM: Ch[n,128] = fp16( A[n,128] @ W[128,128]^T + b ), f32 acc.
// Block tile 128 rows x 128 cols, 4 waves: wave (rowhalf=wid>>1, colhalf=wid&1)
// computes 64x64 via 4x4 grid of 16x16x32 f16 MFMAs. colhalf == head; alpha
// epilogue reduces (acc+bias)·att over the wave's 64 cols (16-lane shfl).
// A-frag: m=lane&15, k=quad*8+j ; B-frag: n=lane&15, k=quad*8+j = W[n][k..k+8].
template <typename T>
__global__ __launch_bounds__(256) void gemm_mfma(const T* __restrict__ A,
    const float* __restrict__ W, const float* __restrict__ b,
    const float* __restrict__ attl, const float* __restrict__ attr,
    __half* __restrict__ Ch, float* __restrict__ al, float* __restrict__ ar,
    int nrows) {
  __shared__ __half Ah[128][40];   // K-chunk [row][kk], pad 40: 16B-aligned rows,
  __shared__ __half Bh[128][40];   // frag reads 2-way conflict only (free)
  int tid = threadIdx.x;
  int lane = tid & 63, wid = tid >> 6;
  int quad = lane >> 4, col = lane & 15;
  int r0 = blockIdx.x * 128;
  int rowhalf = wid >> 1, colhalf = wid & 1;
  floatx4 acc[4][4] = {};          // [rt][ct]
  for (int kc = 0; kc < 128; kc += 32) {
    for (int i = tid; i < 512; i += 256) {
      int row = i >> 2, seg = i & 3;     // 8 elements per slot
      int gr = r0 + row;
      float4 v0, v1;
      if (gr < nrows) {
        const T* p = A + (size_t)gr * 128 + kc + seg * 8;
        v0 = load4(p); v1 = load4(p + 4);
      } else { v0 = make_float4(0.f,0.f,0.f,0.f); v1 = v0; }
      __half2 h0 = __floats2half2_rn(v0.x, v0.y), h1 = __floats2half2_rn(v0.z, v0.w);
      __half2 h2 = __floats2half2_rn(v1.x, v1.y), h3 = __floats2half2_rn(v1.z, v1.w);
      uint4 pk; pk.x = *(unsigned*)&h0; pk.y = *(unsigned*)&h1;
      pk.z = *(unsigned*)&h2; pk.w = *(unsigned*)&h3;
      *(uint4*)&Ah[row][seg * 8] = pk;
      const float* q = W + (size_t)row * 128 + kc + seg * 8;
      float4 w0 = *(const float4*)q, w1 = *(const float4*)(q + 4);
      __half2 g0 = __floats2half2_rn(w0.x, w0.y), g1 = __floats2half2_rn(w0.z, w0.w);
      __half2 g2 = __floats2half2_rn(w1.x, w1.y), g3 = __floats2half2_rn(w1.z, w1.w);
      uint4 qk; qk.x = *(unsigned*)&g0; qk.y = *(unsigned*)&g1;
      qk.z = *(unsigned*)&g2; qk.w = *(unsigned*)&g3;
      *(uint4*)&Bh[row][seg * 8] = qk;
    }
    __syncthreads();
    half8 afr[4], bfr[4];
#pragma unroll
    for (int rt = 0; rt < 4; ++rt)
      afr[rt] = *(const half8*)&Ah[rowhalf * 64 + rt * 16 + col][quad * 8];
#pragma unroll
    for (int ct = 0; ct < 4; ++ct)
      bfr[ct] = *(const half8*)&Bh[colhalf * 64 + ct * 16 + col][quad * 8];
#pragma unroll
    for (int rt = 0; rt < 4; ++rt)
#pragma unroll
      for (int ct = 0; ct < 4; ++ct)
        acc[rt][ct] = __builtin_amdgcn_mfma_f32_16x16x32_f16(afr[rt], bfr[ct],
                                                             acc[rt][ct], 0, 0, 0);
    __syncthreads();
  }
  int head = colhalf;
  float bj[4], wl4[4], wr4[4];
#pragma unroll
  for (int ct = 0; ct < 4; ++ct) {
    int c = ct * 16 + col;               // col within head
    bj[ct] = b[head * 64 + c];
    wl4[ct] = attl[c * 2 + head];
    wr4[ct] = attr[c * 2 + head];
  }
#pragma unroll
  for (int rt = 0; rt < 4; ++rt) {
#pragma unroll
    for (int reg = 0; reg < 4; ++reg) {
      int gr = r0 + rowhalf * 64 + rt * 16 + quad * 4 + reg;
      bool ok = gr < nrows;
      float pl = 0.f, pr = 0.f;
#pragma unroll
      for (int ct = 0; ct < 4; ++ct) {
        float v = acc[rt][ct][reg] + bj[ct];
        pl += v * wl4[ct]; pr += v * wr4[ct];
        if (ok) Ch[(size_t)gr * F + head * 64 + ct * 16 + col] = __float2half(v);
      }
      pl += __shfl_xor(pl, 1, 64); pr += __shfl_xor(pr, 1, 64);
      pl += __shfl_xor(pl, 2, 64); pr += __shfl_xor(pr, 2, 64);
      pl += __shfl_xor(pl, 4, 64); pr += __shfl_xor(pr, 4, 64);
      pl += __shfl_xor(pl, 8, 64); pr += __shfl_xor(pr, 8, 64);
      if (ok && col == 0) { al[gr * 2 + head] = pl; ar[gr * 2 + head] = pr; }
    }
  }
}

// ============ CSR build via two-level bucket sort (all writes coalesced) =======
__global__ __launch_bounds__(256) void bucket_count(const int* __restrict__ ei,
                                                    int* __restrict__ bcnt) {
  __shared__ int h[NBK];
  int tid = threadIdx.x;
  for (int i = tid; i < NBK; i += 256) h[i] = 0;
  __syncthreads();
  int base = blockIdx.x * SC_CHUNK;
  int end = base + SC_CHUNK; if (end > N_EDGES) end = N_EDGES;
  for (int e = base + tid; e < end; e += 256)
    atomicAdd(&h[((unsigned)ei[N_EDGES + e]) >> BK_SHIFT], 1);
  __syncthreads();
  for (int i = tid; i < NBK; i += 256)
    if (h[i]) atomicAdd(&bcnt[i], h[i]);
}

__global__ void bucket_scan(const int* __restrict__ bcnt, int* __restrict__ bbase,
                            int* __restrict__ bcur, int* __restrict__ rowptr) {
  int lane = threadIdx.x;  // 64 threads
  int carry = 0;
  for (int c = 0; c < NBK; c += 64) {
    int i = c + lane;
    int v = (i < NBK) ? bcnt[i] : 0;
    int x = v;
#pragma unroll
    for (int off = 1; off < 64; off <<= 1) {
      int t = __shfl_up(x, off, 64);
      if (lane >= off) x += t;
    }
    int excl = carry + x - v;
    if (i < NBK) { bbase[i] = excl; bcur[i] = excl; }
    carry += __shfl(x, 63, 64);
  }
  if (lane == 0) { bbase[NBK] = carry; rowptr[N_NODES] = N_EDGES; }
}

__global__ __launch_bounds__(256) void bucket_scatter(const int* __restrict__ ei,
    int* __restrict__ bcur, int* __restrict__ pairs) {
  __shared__ int   sd[SC_CHUNK];    // (src << 7) | (dst & 127)
  __shared__ short sb[SC_CHUNK];    // bucket id
  __shared__ int h[NBK], lofs[NBK];
  int tid = threadIdx.x;
  for (int i = tid; i < NBK; i += 256) h[i] = 0;
  __syncthreads();
  int base = blockIdx.x * SC_CHUNK;
  int end = base + SC_CHUNK; if (end > N_EDGES) end = N_EDGES;
  int cnt = end - base;
  for (int e = base + tid; e < end; e += 256) {
    int s = ei[e];
    int d = ei[N_EDGES + e];
    int b = d >> BK_SHIFT;
    sd[e - base] = (s << BK_SHIFT) | (d & (BKSZ - 1));
    sb[e - base] = (short)b;
    atomicAdd(&h[b], 1);
  }
  __syncthreads();
  for (int i = tid; i < NBK; i += 256)
    if (h[i]) { lofs[i] = atomicAdd(&bcur[i], h[i]); h[i] = 0; }
  __syncthreads();
  for (int i = tid; i < cnt; i += 256) {
    int b = sb[i];
    int pos = lofs[b] + atomicAdd(&h[b], 1);
    pairs[pos] = sd[i];
  }
}

__global__ __launch_bounds__(256) void local_sort(const int* __restrict__ bbase,
    const int* __restrict__ pairs, int* __restrict__ rowptr, int* __restrict__ srcs) {
  __shared__ int buf[BK_CAP];
  __shared__ int sorted[BK_CAP];
  __shared__ int hist[BKSZ];
  __shared__ int cur[BKSZ];
  int tid = threadIdx.x;
  int b = blockIdx.x;
  int base = bbase[b];
  int cnt = bbase[b + 1] - base;
  if (cnt > BK_CAP) cnt = BK_CAP;   // statistically impossible; guards LDS
  if (tid < BKSZ) hist[tid] = 0;
  __syncthreads();
  for (int i = tid; i < cnt; i += 256) {
    int p = pairs[base + i];
    buf[i] = p;
    atomicAdd(&hist[p & (BKSZ - 1)], 1);
  }
  __syncthreads();
  if (tid < 64) {
    int lane = tid;
    int carry = 0;
#pragma unroll
    for (int c = 0; c < BKSZ; c += 64) {
      int v = hist[c + lane];
      int x = v;
#pragma unroll
      for (int off = 1; off < 64; off <<= 1) {
        int t = __shfl_up(x, off, 64);
        if (lane >= off) x += t;
      }
      int excl = carry + x - v;
      cur[c + lane] = excl;
      int node = b * BKSZ + c + lane;
      if (node < N_NODES) rowptr[node] = base + excl;
      carry += __shfl(x, 63, 64);
    }
  }
  __syncthreads();
  for (int i = tid; i < cnt; i += 256) {
    int p = buf[i];
    int pos = atomicAdd(&cur[p & (BKSZ - 1)], 1);
    sorted[pos] = p >> BK_SHIFT;
  }
  __syncthreads();
  for (int i = tid; i < cnt; i += 256)
    srcs[base + i] = sorted[i];
}

// ---------------- fused GAT aggregation: one wave per destination node ----------
// 4 edges in parallel: group g=lane>>4 owns edge t+g; 16 lanes/edge each load a
// 16B uint4 (8 fp16 features q*8..q*8+7). Group-reduce via shfl_xor 16/32.
__global__ __launch_bounds__(256) void aggregate_kernel(const int* __restrict__ rowptr,
    const int* __restrict__ srcs, const float* __restrict__ al, const float* __restrict__ ar,
    const __half* __restrict__ xh, __half* __restrict__ out, int n) {
  __shared__ float ebuf[4][2][64];
  __shared__ int   sbuf[4][64];
  int tid = threadIdx.x;
  int wid = tid >> 6, lane = tid & 63;
  int g = lane >> 4, q = lane & 15;
  int head = q >> 3;                    // q<8 → features 0..63 (head 0)
  int node = blockIdx.x * 4 + wid;
  if (node >= n) return;
  int start = rowptr[node], end = rowptr[node + 1];
  float2 arv = *(const float2*)(ar + (size_t)node * 2);
  float ar0 = arv.x, ar1 = arv.y;
  const float* wrow = &ebuf[wid][head][0];
  const __half* xbase = xh + q * 8;
  float acc[8] = {};
  float dl0 = 0.f, dl1 = 0.f;
  for (int c = start; c < end; c += 64) {
    int j = c + lane;
    float e0 = 0.f, e1 = 0.f; int soff = 0;
    if (j < end) {
      int s = srcs[j];
      soff = s << BK_SHIFT;             // s * F
      float2 a = *(const float2*)(al + (size_t)s * 2);
      float s0 = a.x + ar0; s0 = (s0 > 0.f) ? s0 : SLOPE * s0;
      float s1 = a.y + ar1; s1 = (s1 > 0.f) ? s1 : SLOPE * s1;
      e0 = __expf(s0); e1 = __expf(s1);
    }
    dl0 += e0; dl1 += e1;
    ebuf[wid][0][lane] = e0; ebuf[wid][1][lane] = e1; sbuf[wid][lane] = soff;
    __builtin_amdgcn_wave_barrier();
    int cend = end - c; if (cend > 64) cend = 64;
#pragma unroll 4
    for (int t = 0; t < cend; t += 4) {
      int te = t + g;
      if (te < cend) {
        int so = sbuf[wid][te];
        float w = wrow[te];
        uint4 u = *(const uint4*)(xbase + so);
        const __half2* hh = (const __half2*)&u;
        float2 f0 = __half22float2(hh[0]);
        float2 f1 = __half22float2(hh[1]);
        float2 f2 = __half22float2(hh[2]);
        float2 f3 = __half22float2(hh[3]);
        acc[0] += w * f0.x; acc[1] += w * f0.y;
        acc[2] += w * f1.x; acc[3] += w * f1.y;
        acc[4] += w * f2.x; acc[5] += w * f2.y;
        acc[6] += w * f3.x; acc[7] += w * f3.y;
      }
    }
    __builtin_amdgcn_wave_barrier();
  }
#pragma unroll
  for (int off = 32; off > 0; off >>= 1) {
    dl0 += __shfl_xor(dl0, off, 64);
    dl1 += __shfl_xor(dl1, off, 64);
  }
#pragma unroll
  for (int k = 0; k < 8; ++k) {
    acc[k] += __shfl_xor(acc[k], 16, 64);
    acc[k] += __shfl_xor(acc[k], 32, 64);
  }
  if (g == 0) {
    float d = (head == 0) ? dl0 : dl1;
    float inv = 1.f / (d + EPS_DEN);
    __half2 o0 = __floats2half2_rn(fmaxf(acc[0] * inv, 0.f), fmaxf(acc[1] * inv, 0.f));
    __half2 o1 = __floats2half2_rn(fmaxf(acc[2] * inv, 0.f), fmaxf(acc[3] * inv, 0.f));
    __half2 o2 = __floats2half2_rn(fmaxf(acc[4] * inv, 0.f), fmaxf(acc[5] * inv, 0.f));
    __half2 o3 = __floats2half2_rn(fmaxf(acc[6] * inv, 0.f), fmaxf(acc[7] * inv, 0.f));
    uint4 pack;
    pack.x = *(unsigned*)&o0; pack.y = *(unsigned*)&o1;
    pack.z = *(unsigned*)&o2; pack.w = *(unsigned*)&o3;
    *(uint4*)(out + (size_t)node * F + q * 8) = pack;
  }
}

// ---------------- combine post_mp weights: Wc = Wp2@Wp1 (no activation between!)
__global__ void combine_kernel(const float* __restrict__ Wp1, const float* __restrict__ bp1,
    const float* __restrict__ Wp2, const float* __restrict__ bp2,
    float* __restrict__ Wct, float* __restrict__ bc) {
  int idx = blockIdx.x * 256 + threadIdx.x;
  if (blockIdx.x < 20) {                 // 5120 Wc entries
    int o = idx >> 7, k = idx & 127;
    float s = 0.f;
#pragma unroll 8
    for (int j = 0; j < 64; ++j) s += Wp2[o * 64 + j] * Wp1[j * 128 + k];
    Wct[k * 48 + o] = s;
  } else if (threadIdx.x < OUT_DIM) {    // bc
    int o = threadIdx.x;
    float s = bp2[o];
    for (int j = 0; j < 64; ++j) s += Wp2[o * 64 + j] * bp1[j];
    bc[o] = s;
  }
}

// ---------------- post GEMM + log_softmax: out[n,40] = h[n,128]@Wc^T + bc ------
__global__ __launch_bounds__(256) void post_kernel(const __half* __restrict__ h,
    const float* __restrict__ Wct_g, const float* __restrict__ bc,
    float* __restrict__ out, int n) {
  __shared__ float Wct[128 * 48];        // [k][o] padded to 48 → 24 KB
  __shared__ float hs[128 * 33];         // [node][kk] kk-chunk of 32, pad 33
  int tid = threadIdx.x;
#pragma unroll
  for (int r = 0; r < 24; ++r) {
    int i = tid + 256 * r;               // 0..6143
    Wct[i] = Wct_g[i];
  }
  int tx = tid & 7, ty = tid >> 3;
  int base = blockIdx.x * 128;
  float z[4][5] = {};
  for (int kc = 0; kc < 128; kc += 32) {
    __syncthreads();
#pragma unroll
    for (int r = 0; r < 16; ++r) {
      int i = tid + 256 * r;             // 0..4095
      int nd = i >> 5, kk = i & 31;
      int gn = base + nd;
      hs[nd * 33 + kk] = (gn < n) ? __half2float(h[(size_t)gn * F + kc + kk]) : 0.f;
    }
    __syncthreads();
#pragma unroll 8
    for (int kk = 0; kk < 32; ++kk) {
      float a[4], b[5];
#pragma unroll
      for (int i = 0; i < 4; ++i) a[i] = hs[(ty * 4 + i) * 33 + kk];
#pragma unroll
      for (int c = 0; c < 5; ++c) b[c] = Wct[(kc + kk) * 48 + tx * 5 + c];
#pragma unroll
      for (int i = 0; i < 4; ++i)
#pragma unroll
        for (int c = 0; c < 5; ++c) z[i][c] += a[i] * b[c];
    }
  }
  float bcv[5];
#pragma unroll
  for (int c = 0; c < 5; ++c) bcv[c] = bc[tx * 5 + c];
#pragma unroll
  for (int i = 0; i < 4; ++i) {
    int node = base + ty * 4 + i;
    if (node >= n) continue;
    float zc[5], m = -INFINITY;
#pragma unroll
    for (int c = 0; c < 5; ++c) { zc[c] = z[i][c] + bcv[c]; m = fmaxf(m, zc[c]); }
    m = fmaxf(m, __shfl_xor(m, 1, 64));
    m = fmaxf(m, __shfl_xor(m, 2, 64));
    m = fmaxf(m, __shfl_xor(m, 4, 64));
    float s = 0.f;
#pragma unroll
    for (int c = 0; c < 5; ++c) s += __expf(zc[c] - m);
    s += __shfl_xor(s, 1, 64);
    s += __shfl_xor(s, 2, 64);
    s += __shfl_xor(s, 4, 64);
    float ls = logf(s);
#pragma unroll
    for (int c = 0; c < 5; ++c)
      out[(size_t)node * OUT_DIM + tx * 5 + c] = zc[c] - m - ls;
  }
}

extern "C" void kernel_launch(void* const* d_in, const int* in_sizes, int n_in,
                              void* d_out, int out_size, void* d_ws, size_t ws_size,
                              hipStream_t stream) {
  const float* x   = (const float*)d_in[0];
  const int*   ei  = (const int*)d_in[1];
  const float* W1  = (const float*)d_in[2];
  const float* b1  = (const float*)d_in[3];
  const float* al1 = (const float*)d_in[4];
  const float* ar1 = (const float*)d_in[5];
  const float* W2  = (const float*)d_in[6];
  const float* b2  = (const float*)d_in[7];
  const float* al2 = (const float*)d_in[8];
  const float* ar2 = (const float*)d_in[9];
  const float* Wp1 = (const float*)d_in[10];
  const float* bp1 = (const float*)d_in[11];
  const float* Wp2 = (const float*)d_in[12];
  const float* bp2 = (const float*)d_in[13];
  float* out = (float*)d_out;

  float* al    = (float*)d_ws;                       // [N,2]
  float* ar    = al + (size_t)N_NODES * 2;           // [N,2]
  float* Wct   = ar + (size_t)N_NODES * 2;           // [128*48]
  float* bc    = Wct + 128 * 48;                     // [40] (pad to 64)
  int*   rowptr= (int*)(bc + 64);                    // [N+1]
  int*   srcs  = rowptr + N_NODES + 1;               // [E]
  int*   pairs = srcs + N_EDGES;                     // [E]
  int*   bcnt  = pairs + N_EDGES;                    // [NBK]
  int*   bbase = bcnt + NBK;                         // [NBK+1]
  int*   bcur  = bbase + NBK + 1;                    // [NBK]
  uintptr_t pp = ((uintptr_t)(bcur + NBK) + 255) & ~(uintptr_t)255;
  __half* xh   = (__half*)pp;                        // xt fp16   [N,128]
  __half* hb   = xh + (size_t)N_NODES * F;           // h  fp16   [N,128]

  // ---- CSR by destination via bucket sort (edge_index shared by both layers) --
  hipMemsetAsync(bcnt, 0, NBK * sizeof(int), stream);
  bucket_count<<<SC_BLOCKS, 256, 0, stream>>>(ei, bcnt);
  bucket_scan<<<1, 64, 0, stream>>>(bcnt, bbase, bcur, rowptr);
  bucket_scatter<<<SC_BLOCKS, 256, 0, stream>>>(ei, bcur, pairs);
  local_sort<<<NBK, 256, 0, stream>>>(bbase, pairs, rowptr, srcs);
  combine_kernel<<<21, 256, 0, stream>>>(Wp1, bp1, Wp2, bp2, Wct, bc);

  int ggrid = (N_NODES + 127) / 128;   // 391
  int nwgrid = (N_NODES + 3) / 4;      // 4 node-waves per 256-thread block

  // ---- layer 1 ----
  gemm_mfma<float><<<ggrid, 256, 0, stream>>>(x, W1, b1, al1, ar1, xh, al, ar, N_NODES);
  aggregate_kernel<<<nwgrid, 256, 0, stream>>>(rowptr, srcs, al, ar, xh, hb, N_NODES);
  // ---- layer 2 ----
  gemm_mfma<__half><<<ggrid, 256, 0, stream>>>(hb, W2, b2, al2, ar2, xh, al, ar, N_NODES);
  aggregate_kernel<<<nwgrid, 256, 0, stream>>>(rowptr, srcs, al, ar, xh, hb, N_NODES);
  // ---- post_mp + log_softmax ----
  post_kernel<<<(N_NODES + 127) / 128, 256, 0, stream>>>(hb, Wct, bc, out, N_NODES);
}

// Round 8
// 237.193 us; speedup vs baseline: 3.4904x; 1.1456x over previous
//
#include <hip/hip_runtime.h>
#include <hip/hip_fp16.h>
#include <cmath>

#define N_NODES 50000
#define N_EDGES 800000
#define F 128          // HEADS*HID
#define OUT_DIM 40
#define SLOPE 0.2f
#define EPS_DEN 1e-16f

#define BK_SHIFT 7
#define BKSZ 128                         // nodes per bucket
#define NBK ((N_NODES + BKSZ - 1) / BKSZ)  // 391
#define BK_CAP2 2560                     // fixed bucket capacity (mean 2048 + 11 sigma)
#define SC_CHUNK 2500                    // edges per scatter block
#define SC_BLOCKS ((N_EDGES + SC_CHUNK - 1) / SC_CHUNK)  // 320

typedef _Float16 half8 __attribute__((ext_vector_type(8)));
typedef float floatx4 __attribute__((ext_vector_type(4)));

// ---- staging loaders: 4 consecutive elements as float4 ----
__device__ inline float4 load4(const float* p) { return *(const float4*)p; }
__device__ inline float4 load4(const __half* p) {
  uint2 u = *(const uint2*)p;
  float2 a = __half22float2(*(__half2*)&u.x);
  float2 b = __half22float2(*(__half2*)&u.y);
  return make_float4(a.x, a.y, b.x, b.y);
}

// ------- MFMA GEMM: Ch[n,128] = fp16( A[n,128] @ W[128,128]^T + b ), f32 acc.
template <typename T>
__global__ __launch_bounds__(256) void gemm_mfma(const T* __restrict__ A,
    const float* __restrict__ W, const float* __restrict__ b,
    const float* __restrict__ attl, const float* __restrict__ attr,
    __half* __restrict__ Ch, float* __restrict__ al, float* __restrict__ ar,
    int nrows) {
  __shared__ __half Ah[128][40];   // K-chunk [row][kk], pad 40: 16B-aligned rows
  __shared__ __half Bh[128][40];
  int tid = threadIdx.x;
  int lane = tid & 63, wid = tid >> 6;
  int quad = lane >> 4, col = lane & 15;
  int r0 = blockIdx.x * 128;
  int rowhalf = wid >> 1, colhalf = wid & 1;
  floatx4 acc[4][4] = {};          // [rt][ct]
  for (int kc = 0; kc < 128; kc += 32) {
    for (int i = tid; i < 512; i += 256) {
      int row = i >> 2, seg = i & 3;     // 8 elements per slot
      int gr = r0 + row;
      float4 v0, v1;
      if (gr < nrows) {
        const T* p = A + (size_t)gr * 128 + kc + seg * 8;
        v0 = load4(p); v1 = load4(p + 4);
      } else { v0 = make_float4(0.f,0.f,0.f,0.f); v1 = v0; }
      __half2 h0 = __floats2half2_rn(v0.x, v0.y), h1 = __floats2half2_rn(v0.z, v0.w);
      __half2 h2 = __floats2half2_rn(v1.x, v1.y), h3 = __floats2half2_rn(v1.z, v1.w);
      uint4 pk; pk.x = *(unsigned*)&h0; pk.y = *(unsigned*)&h1;
      pk.z = *(unsigned*)&h2; pk.w = *(unsigned*)&h3;
      *(uint4*)&Ah[row][seg * 8] = pk;
      const float* q = W + (size_t)row * 128 + kc + seg * 8;
      float4 w0 = *(const float4*)q, w1 = *(const float4*)(q + 4);
      __half2 g0 = __floats2half2_rn(w0.x, w0.y), g1 = __floats2half2_rn(w0.z, w0.w);
      __half2 g2 = __floats2half2_rn(w1.x, w1.y), g3 = __floats2half2_rn(w1.z, w1.w);
      uint4 qk; qk.x = *(unsigned*)&g0; qk.y = *(unsigned*)&g1;
      qk.z = *(unsigned*)&g2; qk.w = *(unsigned*)&g3;
      *(uint4*)&Bh[row][seg * 8] = qk;
    }
    __syncthreads();
    half8 afr[4], bfr[4];
#pragma unroll
    for (int rt = 0; rt < 4; ++rt)
      afr[rt] = *(const half8*)&Ah[rowhalf * 64 + rt * 16 + col][quad * 8];
#pragma unroll
    for (int ct = 0; ct < 4; ++ct)
      bfr[ct] = *(const half8*)&Bh[colhalf * 64 + ct * 16 + col][quad * 8];
#pragma unroll
    for (int rt = 0; rt < 4; ++rt)
#pragma unroll
      for (int ct = 0; ct < 4; ++ct)
        acc[rt][ct] = __builtin_amdgcn_mfma_f32_16x16x32_f16(afr[rt], bfr[ct],
                                                             acc[rt][ct], 0, 0, 0);
    __syncthreads();
  }
  int head = colhalf;
  float bj[4], wl4[4], wr4[4];
#pragma unroll
  for (int ct = 0; ct < 4; ++ct) {
    int c = ct * 16 + col;               // col within head
    bj[ct] = b[head * 64 + c];
    wl4[ct] = attl[c * 2 + head];
    wr4[ct] = attr[c * 2 + head];
  }
#pragma unroll
  for (int rt = 0; rt < 4; ++rt) {
#pragma unroll
    for (int reg = 0; reg < 4; ++reg) {
      int gr = r0 + rowhalf * 64 + rt * 16 + quad * 4 + reg;
      bool ok = gr < nrows;
      float pl = 0.f, pr = 0.f;
#pragma unroll
      for (int ct = 0; ct < 4; ++ct) {
        float v = acc[rt][ct][reg] + bj[ct];
        pl += v * wl4[ct]; pr += v * wr4[ct];
        if (ok) Ch[(size_t)gr * F + head * 64 + ct * 16 + col] = __float2half(v);
      }
      pl += __shfl_xor(pl, 1, 64); pr += __shfl_xor(pr, 1, 64);
      pl += __shfl_xor(pl, 2, 64); pr += __shfl_xor(pr, 2, 64);
      pl += __shfl_xor(pl, 4, 64); pr += __shfl_xor(pr, 4, 64);
      pl += __shfl_xor(pl, 8, 64); pr += __shfl_xor(pr, 8, 64);
      if (ok && col == 0) { al[gr * 2 + head] = pl; ar[gr * 2 + head] = pr; }
    }
  }
}

// ============ CSR build: fixed-capacity buckets (no count/scan passes) =========
__global__ __launch_bounds__(256) void bucket_scatter(const int* __restrict__ ei,
    int* __restrict__ bcur, int* __restrict__ pairs) {
  __shared__ int   sd[SC_CHUNK];    // (src << 7) | (dst & 127)
  __shared__ short sb[SC_CHUNK];    // bucket id
  __shared__ int h[NBK], lofs[NBK];
  int tid = threadIdx.x;
  for (int i = tid; i < NBK; i += 256) h[i] = 0;
  __syncthreads();
  int base = blockIdx.x * SC_CHUNK;
  int end = base + SC_CHUNK; if (end > N_EDGES) end = N_EDGES;
  int cnt = end - base;
  for (int e = base + tid; e < end; e += 256) {
    int s = ei[e];
    int d = ei[N_EDGES + e];
    int b = d >> BK_SHIFT;
    sd[e - base] = (s << BK_SHIFT) | (d & (BKSZ - 1));
    sb[e - base] = (short)b;
    atomicAdd(&h[b], 1);
  }
  __syncthreads();
  for (int i = tid; i < NBK; i += 256)
    if (h[i]) { lofs[i] = i * BK_CAP2 + atomicAdd(&bcur[i], h[i]); h[i] = 0; }
  __syncthreads();
  for (int i = tid; i < cnt; i += 256) {
    int b = sb[i];
    int pos = lofs[b] + atomicAdd(&h[b], 1);
    pairs[pos] = sd[i];
  }
}

// one block per bucket: exact sort by dst in LDS; emits rowstart/rowend + srcs
__global__ __launch_bounds__(256) void local_sort(const int* __restrict__ bcur,
    const int* __restrict__ pairs, int* __restrict__ rowstart,
    int* __restrict__ rowend, int* __restrict__ srcs) {
  __shared__ int buf[BK_CAP2];
  __shared__ int sorted[BK_CAP2];
  __shared__ int hist[BKSZ];
  __shared__ int cur[BKSZ];
  int tid = threadIdx.x;
  int b = blockIdx.x;
  int base = b * BK_CAP2;
  int cnt = bcur[b];
  if (cnt > BK_CAP2) cnt = BK_CAP2;   // statistically impossible; guards LDS
  if (tid < BKSZ) hist[tid] = 0;
  __syncthreads();
  for (int i = tid; i < cnt; i += 256) {
    int p = pairs[base + i];
    buf[i] = p;
    atomicAdd(&hist[p & (BKSZ - 1)], 1);
  }
  __syncthreads();
  if (tid < 64) {
    int lane = tid;
    int carry = 0;
#pragma unroll
    for (int c = 0; c < BKSZ; c += 64) {
      int v = hist[c + lane];
      int x = v;
#pragma unroll
      for (int off = 1; off < 64; off <<= 1) {
        int t = __shfl_up(x, off, 64);
        if (lane >= off) x += t;
      }
      int excl = carry + x - v;
      cur[c + lane] = excl;
      int node = b * BKSZ + c + lane;
      if (node < N_NODES) {
        rowstart[node] = base + excl;
        rowend[node]   = base + excl + v;
      }
      carry += __shfl(x, 63, 64);
    }
  }
  __syncthreads();
  for (int i = tid; i < cnt; i += 256) {
    int p = buf[i];
    int pos = atomicAdd(&cur[p & (BKSZ - 1)], 1);
    sorted[pos] = p >> BK_SHIFT;
  }
  __syncthreads();
  for (int i = tid; i < cnt; i += 256)
    srcs[base + i] = sorted[i];
}

// ---------------- fused GAT aggregation: one wave per destination node ----------
__global__ __launch_bounds__(256) void aggregate_kernel(const int* __restrict__ rowstart,
    const int* __restrict__ rowend, const int* __restrict__ srcs,
    const float* __restrict__ al, const float* __restrict__ ar,
    const __half* __restrict__ xh, __half* __restrict__ out, int n) {
  __shared__ float ebuf[4][2][64];
  __shared__ int   sbuf[4][64];
  int tid = threadIdx.x;
  int wid = tid >> 6, lane = tid & 63;
  int g = lane >> 4, q = lane & 15;
  int head = q >> 3;                    // q<8 → features 0..63 (head 0)
  int node = blockIdx.x * 4 + wid;
  if (node >= n) return;
  int start = rowstart[node], end = rowend[node];
  float2 arv = *(const float2*)(ar + (size_t)node * 2);
  float ar0 = arv.x, ar1 = arv.y;
  const float* wrow = &ebuf[wid][head][0];
  const __half* xbase = xh + q * 8;
  float acc[8] = {};
  float dl0 = 0.f, dl1 = 0.f;
  for (int c = start; c < end; c += 64) {
    int j = c + lane;
    float e0 = 0.f, e1 = 0.f; int soff = 0;
    if (j < end) {
      int s = srcs[j];
      soff = s << BK_SHIFT;             // s * F
      float2 a = *(const float2*)(al + (size_t)s * 2);
      float s0 = a.x + ar0; s0 = (s0 > 0.f) ? s0 : SLOPE * s0;
      float s1 = a.y + ar1; s1 = (s1 > 0.f) ? s1 : SLOPE * s1;
      e0 = __expf(s0); e1 = __expf(s1);
    }
    dl0 += e0; dl1 += e1;
    ebuf[wid][0][lane] = e0; ebuf[wid][1][lane] = e1; sbuf[wid][lane] = soff;
    __builtin_amdgcn_wave_barrier();
    int cend = end - c; if (cend > 64) cend = 64;
#pragma unroll 4
    for (int t = 0; t < cend; t += 4) {
      int te = t + g;
      if (te < cend) {
        int so = sbuf[wid][te];
        float w = wrow[te];
        uint4 u = *(const uint4*)(xbase + so);
        const __half2* hh = (const __half2*)&u;
        float2 f0 = __half22float2(hh[0]);
        float2 f1 = __half22float2(hh[1]);
        float2 f2 = __half22float2(hh[2]);
        float2 f3 = __half22float2(hh[3]);
        acc[0] += w * f0.x; acc[1] += w * f0.y;
        acc[2] += w * f1.x; acc[3] += w * f1.y;
        acc[4] += w * f2.x; acc[5] += w * f2.y;
        acc[6] += w * f3.x; acc[7] += w * f3.y;
      }
    }
    __builtin_amdgcn_wave_barrier();
  }
#pragma unroll
  for (int off = 32; off > 0; off >>= 1) {
    dl0 += __shfl_xor(dl0, off, 64);
    dl1 += __shfl_xor(dl1, off, 64);
  }
#pragma unroll
  for (int k = 0; k < 8; ++k) {
    acc[k] += __shfl_xor(acc[k], 16, 64);
    acc[k] += __shfl_xor(acc[k], 32, 64);
  }
  if (g == 0) {
    float d = (head == 0) ? dl0 : dl1;
    float inv = 1.f / (d + EPS_DEN);
    __half2 o0 = __floats2half2_rn(fmaxf(acc[0] * inv, 0.f), fmaxf(acc[1] * inv, 0.f));
    __half2 o1 = __floats2half2_rn(fmaxf(acc[2] * inv, 0.f), fmaxf(acc[3] * inv, 0.f));
    __half2 o2 = __floats2half2_rn(fmaxf(acc[4] * inv, 0.f), fmaxf(acc[5] * inv, 0.f));
    __half2 o3 = __floats2half2_rn(fmaxf(acc[6] * inv, 0.f), fmaxf(acc[7] * inv, 0.f));
    uint4 pack;
    pack.x = *(unsigned*)&o0; pack.y = *(unsigned*)&o1;
    pack.z = *(unsigned*)&o2; pack.w = *(unsigned*)&o3;
    *(uint4*)(out + (size_t)node * F + q * 8) = pack;
  }
}

// ---- combine post_mp weights: Wc = Wp2@Wp1 → fp16 B-frag layout [o][k] --------
__global__ void combine_kernel(const float* __restrict__ Wp1, const float* __restrict__ bp1,
    const float* __restrict__ Wp2, const float* __restrict__ bp2,
    __half* __restrict__ Wch, float* __restrict__ bc) {
  int idx = blockIdx.x * 256 + threadIdx.x;
  if (blockIdx.x < 24) {                 // 48*128 = 6144 entries
    int o = idx >> 7, k = idx & 127;
    float s = 0.f;
    if (o < OUT_DIM) {
#pragma unroll 8
      for (int j = 0; j < 64; ++j) s += Wp2[o * 64 + j] * Wp1[j * 128 + k];
    }
    Wch[o * 128 + k] = __float2half(s);
  } else if (threadIdx.x < 48) {
    int o = threadIdx.x;
    if (o < OUT_DIM) {
      float s = bp2[o];
      for (int j = 0; j < 64; ++j) s += Wp2[o * 64 + j] * bp1[j];
      bc[o] = s;
    } else {
      bc[o] = -1e30f;                    // pad cols: exp(z-m)=0 in softmax
    }
  }
}

// ---- MFMA post + fused log_softmax: out[n,40] = h[n,128] @ Wc^T + bc ----------
// No LDS: A-frags straight from hb (16B/lane), B-frags from L2-hot Wch.
__global__ __launch_bounds__(256) void post_mfma(const __half* __restrict__ hb,
    const __half* __restrict__ Wch, const float* __restrict__ bc,
    float* __restrict__ out, int n) {
  int tid = threadIdx.x;
  int lane = tid & 63, wid = tid >> 6;
  int quad = lane >> 4, col = lane & 15;
  int base = blockIdx.x * 64 + wid * 16;
  int arow = base + col;                 // A-frag m-index = lane&15
  int asafe = (arow < n) ? arow : (n - 1);
  floatx4 acc[3] = {};
#pragma unroll
  for (int kc = 0; kc < 128; kc += 32) {
    half8 afr = *(const half8*)(hb + (size_t)asafe * F + kc + quad * 8);
#pragma unroll
    for (int ct = 0; ct < 3; ++ct) {
      half8 bfr = *(const half8*)(Wch + (size_t)(ct * 16 + col) * 128 + kc + quad * 8);
      acc[ct] = __builtin_amdgcn_mfma_f32_16x16x32_f16(afr, bfr, acc[ct], 0, 0, 0);
    }
  }
  float bcv[3];
#pragma unroll
  for (int ct = 0; ct < 3; ++ct) bcv[ct] = bc[ct * 16 + col];
#pragma unroll
  for (int reg = 0; reg < 4; ++reg) {
    int row = base + quad * 4 + reg;     // C row = quad*4+reg
    float z[3], m = -INFINITY;
#pragma unroll
    for (int ct = 0; ct < 3; ++ct) { z[ct] = acc[ct][reg] + bcv[ct]; m = fmaxf(m, z[ct]); }
    m = fmaxf(m, __shfl_xor(m, 1, 64));
    m = fmaxf(m, __shfl_xor(m, 2, 64));
    m = fmaxf(m, __shfl_xor(m, 4, 64));
    m = fmaxf(m, __shfl_xor(m, 8, 64));
    float s = 0.f;
#pragma unroll
    for (int ct = 0; ct < 3; ++ct) s += __expf(z[ct] - m);
    s += __shfl_xor(s, 1, 64);
    s += __shfl_xor(s, 2, 64);
    s += __shfl_xor(s, 4, 64);
    s += __shfl_xor(s, 8, 64);
    float ls = logf(s);
    if (row < n) {
#pragma unroll
      for (int ct = 0; ct < 3; ++ct) {
        int o = ct * 16 + col;
        if (o < OUT_DIM) out[(size_t)row * OUT_DIM + o] = z[ct] - m - ls;
      }
    }
  }
}

extern "C" void kernel_launch(void* const* d_in, const int* in_sizes, int n_in,
                              void* d_out, int out_size, void* d_ws, size_t ws_size,
                              hipStream_t stream) {
  const float* x   = (const float*)d_in[0];
  const int*   ei  = (const int*)d_in[1];
  const float* W1  = (const float*)d_in[2];
  const float* b1  = (const float*)d_in[3];
  const float* al1 = (const float*)d_in[4];
  const float* ar1 = (const float*)d_in[5];
  const float* W2  = (const float*)d_in[6];
  const float* b2  = (const float*)d_in[7];
  const float* al2 = (const float*)d_in[8];
  const float* ar2 = (const float*)d_in[9];
  const float* Wp1 = (const float*)d_in[10];
  const float* bp1 = (const float*)d_in[11];
  const float* Wp2 = (const float*)d_in[12];
  const float* bp2 = (const float*)d_in[13];
  float* out = (float*)d_out;

  float* al    = (float*)d_ws;                       // [N,2]
  float* ar    = al + (size_t)N_NODES * 2;           // [N,2]
  __half* Wch  = (__half*)(ar + (size_t)N_NODES * 2);// [48*128] fp16
  float* bc    = (float*)(Wch + 48 * 128);           // [48]
  int* rowstart= (int*)(bc + 48);                    // [N]
  int* rowend  = rowstart + N_NODES;                 // [N]
  int* bcur    = rowend + N_NODES;                   // [NBK]
  int* srcs    = bcur + NBK + 1;                     // [NBK*BK_CAP2]
  int* pairs   = srcs + NBK * BK_CAP2;               // [NBK*BK_CAP2]
  uintptr_t pp = ((uintptr_t)(pairs + NBK * BK_CAP2) + 255) & ~(uintptr_t)255;
  __half* xh   = (__half*)pp;                        // xt fp16   [N,128]
  __half* hb   = xh + (size_t)N_NODES * F;           // h  fp16   [N,128]

  // ---- CSR by destination: fixed-capacity bucket sort ----
  hipMemsetAsync(bcur, 0, NBK * sizeof(int), stream);
  bucket_scatter<<<SC_BLOCKS, 256, 0, stream>>>(ei, bcur, pairs);
  local_sort<<<NBK, 256, 0, stream>>>(bcur, pairs, rowstart, rowend, srcs);
  combine_kernel<<<25, 256, 0, stream>>>(Wp1, bp1, Wp2, bp2, Wch, bc);

  int ggrid = (N_NODES + 127) / 128;   // 391
  int nwgrid = (N_NODES + 3) / 4;      // 4 node-waves per 256-thread block

  // ---- layer 1 ----
  gemm_mfma<float><<<ggrid, 256, 0, stream>>>(x, W1, b1, al1, ar1, xh, al, ar, N_NODES);
  aggregate_kernel<<<nwgrid, 256, 0, stream>>>(rowstart, rowend, srcs, al, ar, xh, hb, N_NODES);
  // ---- layer 2 ----
  gemm_mfma<__half><<<ggrid, 256, 0, stream>>>(hb, W2, b2, al2, ar2, xh, al, ar, N_NODES);
  aggregate_kernel<<<nwgrid, 256, 0, stream>>>(rowstart, rowend, srcs, al, ar, xh, hb, N_NODES);
  // ---- post_mp + log_softmax (MFMA, no LDS) ----
  post_mfma<<<(N_NODES + 63) / 64, 256, 0, stream>>>(hb, Wch, bc, out, N_NODES);
}